// Round 6
// baseline (601.663 us; speedup 1.0000x reference)
//
#include <hip/hip_runtime.h>

typedef __attribute__((ext_vector_type(8))) short bf16x8;
typedef __attribute__((ext_vector_type(4))) float f32x4;

#define NN 50000
#define HH 128
#define EB 128   // edges per block in edge kernel (32 rows per wave)

static __device__ __forceinline__ unsigned short f2bf(float f) {
  unsigned u = __builtin_bit_cast(unsigned, f);
  u = u + 0x7FFFu + ((u >> 16) & 1u);
  return (unsigned short)(u >> 16);
}

static __device__ __forceinline__ float bf2f(unsigned short b) {
  return __builtin_bit_cast(float, ((unsigned)b) << 16);
}

static __device__ __forceinline__ bf16x8 bfrag(const unsigned short* __restrict__ w,
                                               int kt, int nt, int lane) {
  return *reinterpret_cast<const bf16x8*>(w + (((kt * 8 + nt) * 64 + lane) << 3));
}

// Fused weight swizzle: 10 jobs with K=128 (64 blocks each), 2 jobs with K=512 (256 blocks).
struct SwzJobs {
  const float* src[12];
  unsigned short* dst[12];
};
__global__ void swz_all_kernel(SwzJobs jobs) {
  int b = blockIdx.x;
  int job, blk;
  if (b < 640) { job = b >> 6; blk = b & 63; }
  else { b -= 640; job = 10 + (b >> 8); blk = b & 255; }
  int o = blk * 256 + threadIdx.x;
  int j = o & 7, lane = (o >> 3) & 63, nt = (o >> 9) & 7, kt = o >> 12;
  int row = kt * 32 + (lane >> 4) * 8 + j;
  int col = nt * 16 + (lane & 15);
  jobs.dst[job][o] = f2bf(jobs.src[job][row * 128 + col]);
}

// P/Q precompute: 6 GEMMs out = x @ W (+bias), bf16 row-major output.
struct PQJobs {
  const unsigned short* Wswz[6];
  const float* bias[6];
  unsigned short* out[6];
};
__global__ __launch_bounds__(256) void pq_kernel(const float* __restrict__ x, PQJobs jobs) {
  __shared__ unsigned short As[64][136];
  const int t = threadIdx.x;
  const int n0 = blockIdx.x * 64;
  for (int idx = t; idx < 64 * 32; idx += 256) {
    int e = idx >> 5, c4 = (idx & 31) << 2;
    int row = n0 + e;
    float4 v = make_float4(0.f, 0.f, 0.f, 0.f);
    if (row < NN) v = *reinterpret_cast<const float4*>(x + (long)row * HH + c4);
    *reinterpret_cast<ushort4*>(&As[e][c4]) =
        make_ushort4(f2bf(v.x), f2bf(v.y), f2bf(v.z), f2bf(v.w));
  }
  __syncthreads();
  const int wave = t >> 6, lane = t & 63;
  const int lr = lane & 15, lgp = lane >> 4;
  bf16x8 afr[4];
#pragma unroll
  for (int kt = 0; kt < 4; ++kt)
    afr[kt] = *reinterpret_cast<const bf16x8*>(&As[wave * 16 + lr][kt * 32 + lgp * 8]);
#pragma unroll
  for (int jb = 0; jb < 6; ++jb) {
    f32x4 acc[8];
#pragma unroll
    for (int nt = 0; nt < 8; ++nt) acc[nt] = (f32x4){0.f, 0.f, 0.f, 0.f};
#pragma unroll
    for (int kt = 0; kt < 4; ++kt)
#pragma unroll
      for (int nt = 0; nt < 8; ++nt)
        acc[nt] = __builtin_amdgcn_mfma_f32_16x16x32_bf16(
            afr[kt], bfrag(jobs.Wswz[jb], kt, nt, lane), acc[nt], 0, 0, 0);
    const float* bi = jobs.bias[jb];
    unsigned short* O = jobs.out[jb];
#pragma unroll
    for (int nt = 0; nt < 8; ++nt) {
      int col = nt * 16 + lr;
      float bv = bi ? bi[col] : 0.f;
#pragma unroll
      for (int r = 0; r < 4; ++r) {
        int row = n0 + wave * 16 + lgp * 4 + r;
        if (row < NN) O[(long)row * HH + col] = f2bf(acc[nt][r] + bv);
      }
    }
  }
}

// ---- counting-sort by destination (two-level parallel scan) ----
__global__ void hist3_kernel(const int* __restrict__ eiL, const int* __restrict__ eiM,
                             const int* __restrict__ eiG, int El, int Em, int Eg,
                             int* __restrict__ cnt) {
  int e = blockIdx.x * 256 + threadIdx.x;
  const int* ei; int E, off;
  if (e < El) { ei = eiL; E = El; off = 0; }
  else if (e < El + Em) { e -= El; ei = eiM; E = Em; off = NN; }
  else { e -= El + Em; if (e >= Eg) return; ei = eiG; E = Eg; off = 2 * NN; }
  atomicAdd(cnt + off + ei[E + e], 1);
}

__global__ void scanA_kernel(const int* __restrict__ cnt, int* __restrict__ offs,
                             int* __restrict__ bsum, int n) {
  const int t = threadIdx.x, lane = t & 63, w = t >> 6;
  const int i = blockIdx.x * 1024 + t;
  __shared__ int wsum[16], wpre[16];
  int v = (i < n) ? cnt[i] : 0;
  int inc = v;
#pragma unroll
  for (int d = 1; d < 64; d <<= 1) {
    int o = __shfl_up(inc, d, 64);
    if (lane >= d) inc += o;
  }
  if (lane == 63) wsum[w] = inc;
  __syncthreads();
  if (t == 0) {
    int run = 0;
#pragma unroll
    for (int k = 0; k < 16; ++k) { wpre[k] = run; run += wsum[k]; }
    wsum[0] = run;
  }
  __syncthreads();
  if (i < n) offs[i] = wpre[w] + inc - v;
  if (t == 0) bsum[blockIdx.x] = wsum[0];
}

__global__ void scanB_kernel(int* __restrict__ bsum, int n) {
  const int t = threadIdx.x, lane = t & 63, w = t >> 6;
  __shared__ int wsum[4];
  int v = (t < n) ? bsum[t] : 0;
  int inc = v;
#pragma unroll
  for (int d = 1; d < 64; d <<= 1) {
    int o = __shfl_up(inc, d, 64);
    if (lane >= d) inc += o;
  }
  if (lane == 63) wsum[w] = inc;
  __syncthreads();
  int wo = 0;
  for (int k = 0; k < w; ++k) wo += wsum[k];
  if (t < n) bsum[t] = wo + inc - v;
}

__global__ void scanC_kernel(int* __restrict__ offs, const int* __restrict__ bsum, int n) {
  int i = blockIdx.x * 1024 + threadIdx.x;
  if (i < n) offs[i] += bsum[blockIdx.x];
}

// Scatter into GLOBAL sorted position (concatenated scan): materialize sorted
// src/dst/edge-attr arrays so the edge kernel reads metadata coalesced.
__global__ void scatter3_kernel(const int* __restrict__ eiL, const int* __restrict__ eiM,
                                const int* __restrict__ eiG,
                                const float* __restrict__ eaL, const float* __restrict__ eaM,
                                const float* __restrict__ eaG,
                                int El, int Em, int Eg, int* __restrict__ offs,
                                int* __restrict__ ssrc, int* __restrict__ sdst,
                                float4* __restrict__ sea) {
  int e = blockIdx.x * 256 + threadIdx.x;
  const int* ei; const float* ea; int E, off;
  if (e < El) { ei = eiL; ea = eaL; E = El; off = 0; }
  else if (e < El + Em) { e -= El; ei = eiM; ea = eaM; E = Em; off = NN; }
  else { e -= El + Em; if (e >= Eg) return; ei = eiG; ea = eaG; E = Eg; off = 2 * NN; }
  int d = ei[E + e];
  int p = atomicAdd(offs + off + d, 1);
  sdst[p] = d;
  ssrc[p] = ei[e];
  sea[p] = make_float4(ea[(long)e * 3 + 0], ea[(long)e * 3 + 1], ea[(long)e * 3 + 2], 0.f);
}

// ---- edge kernel: h1 = relu(P[src]+Q[dst]+ea·Wc) summed over dst-segments,
// one atomicAdd per (unique dst, col) into hagg. No MFMA, no barriers in hot loop.
struct EScale {
  const int* ssrc; const int* sdst; const float4* sea;
  const unsigned short *P, *Q;
  const float* Wc;       // W1 rows 256..258 (3x128 fp32)
  float* hag;
  int E; int tbase;
};
struct EParams { EScale s[3]; };
__global__ __launch_bounds__(256) void edge_kernel(EParams prm) {
  __shared__ int srcs[EB], dsts[EB];
  __shared__ float eas[EB][4];
  __shared__ float Wc[384];
  const int t = threadIdx.x;

  // XCD-chunked bijective swizzle over global tile space
  const int nwg = gridDim.x, bid = blockIdx.x;
  const int q = nwg >> 3, r = nwg & 7;
  const int xcd = bid & 7, idx = bid >> 3;
  const int tile = (xcd < r ? xcd * (q + 1) : r * (q + 1) + (xcd - r) * q) + idx;
  const int si = (tile >= prm.s[1].tbase) + (tile >= prm.s[2].tbase);
  const EScale S = prm.s[si];
  const int e0 = (tile - S.tbase) * EB;

  if (t < EB) {
    int ge = e0 + t;
    int d = -1, s = 0;
    float4 e4 = make_float4(0.f, 0.f, 0.f, 0.f);
    if (ge < S.E) { d = S.sdst[ge]; s = S.ssrc[ge]; e4 = S.sea[ge]; }
    dsts[t] = d; srcs[t] = s;
    *reinterpret_cast<float4*>(&eas[t][0]) = e4;
  }
  for (int i = t; i < 384; i += 256) Wc[i] = S.Wc[i];
  __syncthreads();

  const int wave = t >> 6, lane = t & 63;
  const int c2 = lane * 2;
  const float wcA0 = Wc[c2], wcB0 = Wc[c2 + 1];
  const float wcA1 = Wc[128 + c2], wcB1 = Wc[129 + c2];
  const float wcA2 = Wc[256 + c2], wcB2 = Wc[257 + c2];
  const int r0 = wave * 32;

  int cur = -1;
  float aA = 0.f, aB = 0.f, qA = 0.f, qB = 0.f;
  for (int rr = 0; rr < 32; ++rr) {
    int rI = r0 + rr;
    int d = dsts[rI];
    if (d != cur) {
      if (cur >= 0) {
        atomicAdd(S.hag + (long)cur * HH + c2, aA);
        atomicAdd(S.hag + (long)cur * HH + c2 + 1, aB);
      }
      cur = d; aA = aB = 0.f;
      if (d < 0) break;
      ushort2 qv = *reinterpret_cast<const ushort2*>(S.Q + (long)d * HH + c2);
      qA = bf2f(qv.x); qB = bf2f(qv.y);
    }
    int sN = srcs[rI];
    float e0v = eas[rI][0], e1v = eas[rI][1], e2v = eas[rI][2];
    ushort2 p = *reinterpret_cast<const ushort2*>(S.P + (long)sN * HH + c2);
    float vA = bf2f(p.x) + qA + e0v * wcA0 + e1v * wcA1 + e2v * wcA2;
    float vB = bf2f(p.y) + qB + e0v * wcB0 + e1v * wcB1 + e2v * wcB2;
    aA += fmaxf(vA, 0.f);
    aB += fmaxf(vB, 0.f);
  }
  if (cur >= 0) {
    atomicAdd(S.hag + (long)cur * HH + c2, aA);
    atomicAdd(S.hag + (long)cur * HH + c2 + 1, aB);
  }
}

// ---- node kernel: per-scale msg GEMM fused in (band-private LDS, barrier-free) ----
static __device__ __forceinline__ void stage_band_f32(
    const float* __restrict__ src, int n0, int band, int lane,
    unsigned short (*B)[136]) {
#pragma unroll
  for (int rr = 0; rr < 16; ++rr) {
    int row = n0 + band + rr;
    float2 v = make_float2(0.f, 0.f);
    if (row < NN) v = *reinterpret_cast<const float2*>(src + (long)row * HH + lane * 2);
    *reinterpret_cast<ushort2*>(&B[band + rr][lane * 2]) =
        make_ushort2(f2bf(v.x), f2bf(v.y));
  }
}

static __device__ __forceinline__ void scale_chunk(
    const float* __restrict__ H, const unsigned short* __restrict__ W2,
    const float* __restrict__ b2, const int* __restrict__ deg,
    const unsigned short* __restrict__ Wgw, const unsigned short* __restrict__ Wu1w,
    int koff, int n0, int band, int lane, int lr, int lgp,
    unsigned short (*B)[136], f32x4* accG, f32x4* accH) {
  // stage hagg band (fp32 -> bf16), band-private
  stage_band_f32(H, n0, band, lane, B);
  bf16x8 hfr[4];
#pragma unroll
  for (int kt = 0; kt < 4; ++kt)
    hfr[kt] = *reinterpret_cast<const bf16x8*>(&B[band + lr][kt * 32 + lgp * 8]);
  f32x4 mc[8];
#pragma unroll
  for (int nt = 0; nt < 8; ++nt) mc[nt] = (f32x4){0.f, 0.f, 0.f, 0.f};
#pragma unroll
  for (int kt = 0; kt < 4; ++kt)
#pragma unroll
    for (int nt = 0; nt < 8; ++nt)
      mc[nt] = __builtin_amdgcn_mfma_f32_16x16x32_bf16(hfr[kt], bfrag(W2, kt, nt, lane),
                                                       mc[nt], 0, 0, 0);
  // msg = mc + deg*b2 -> bf16 back into same band (C layout), then reload as A-frags
#pragma unroll
  for (int nt = 0; nt < 8; ++nt) {
    int col = nt * 16 + lr;
    float bv = b2[col];
#pragma unroll
    for (int rr = 0; rr < 4; ++rr) {
      int row = n0 + band + lgp * 4 + rr;
      float dg = (row < NN) ? (float)deg[row] : 0.f;
      B[band + lgp * 4 + rr][col] = f2bf(mc[nt][rr] + dg * bv);
    }
  }
  bf16x8 mfr[4];
#pragma unroll
  for (int kt = 0; kt < 4; ++kt)
    mfr[kt] = *reinterpret_cast<const bf16x8*>(&B[band + lr][kt * 32 + lgp * 8]);
#pragma unroll
  for (int kt = 0; kt < 4; ++kt)
#pragma unroll
    for (int nt = 0; nt < 8; ++nt) {
      accG[nt] = __builtin_amdgcn_mfma_f32_16x16x32_bf16(
          mfr[kt], bfrag(Wgw, koff + kt, nt, lane), accG[nt], 0, 0, 0);
      accH[nt] = __builtin_amdgcn_mfma_f32_16x16x32_bf16(
          mfr[kt], bfrag(Wu1w, koff + kt, nt, lane), accH[nt], 0, 0, 0);
    }
}

__global__ __launch_bounds__(256) void node_kernel(
    const float* __restrict__ x,
    const float* __restrict__ hl, const float* __restrict__ hm, const float* __restrict__ hgg,
    const int* __restrict__ cnt,
    const unsigned short* __restrict__ W2a, const unsigned short* __restrict__ W2b,
    const unsigned short* __restrict__ W2c,
    const unsigned short* __restrict__ Wg, const unsigned short* __restrict__ Wu1,
    const unsigned short* __restrict__ Wu2,
    const float* __restrict__ b2a, const float* __restrict__ b2b, const float* __restrict__ b2c,
    const float* __restrict__ bg, const float* __restrict__ bu1, const float* __restrict__ bu2,
    const float* __restrict__ gamma, const float* __restrict__ beta,
    float* __restrict__ out) {
  __shared__ unsigned short B[64][136];
  const int t = threadIdx.x;
  const int n0 = blockIdx.x * 64;
  const int wave = t >> 6, lane = t & 63;
  const int lr = lane & 15, lgp = lane >> 4;
  const int band = wave * 16;

  f32x4 accG[8], accH[8];
#pragma unroll
  for (int nt = 0; nt < 8; ++nt) {
    accG[nt] = (f32x4){0.f, 0.f, 0.f, 0.f};
    accH[nt] = (f32x4){0.f, 0.f, 0.f, 0.f};
  }

  // chunk 0: x
  stage_band_f32(x, n0, band, lane, B);
  {
    bf16x8 afr[4];
#pragma unroll
    for (int kt = 0; kt < 4; ++kt)
      afr[kt] = *reinterpret_cast<const bf16x8*>(&B[band + lr][kt * 32 + lgp * 8]);
#pragma unroll
    for (int kt = 0; kt < 4; ++kt)
#pragma unroll
      for (int nt = 0; nt < 8; ++nt) {
        accG[nt] = __builtin_amdgcn_mfma_f32_16x16x32_bf16(
            afr[kt], bfrag(Wg, kt, nt, lane), accG[nt], 0, 0, 0);
        accH[nt] = __builtin_amdgcn_mfma_f32_16x16x32_bf16(
            afr[kt], bfrag(Wu1, kt, nt, lane), accH[nt], 0, 0, 0);
      }
  }

  // chunks 1-3: per-scale fused msg GEMM + gate/update accumulation
  scale_chunk(hl, W2a, b2a, cnt, Wg, Wu1, 4, n0, band, lane, lr, lgp, B, accG, accH);
  scale_chunk(hm, W2b, b2b, cnt + NN, Wg, Wu1, 8, n0, band, lane, lr, lgp, B, accG, accH);
  scale_chunk(hgg, W2c, b2c, cnt + 2 * NN, Wg, Wu1, 12, n0, band, lane, lr, lgp, B, accG, accH);

  // gate = sigmoid(accG+bg); h1 = relu(accH+bu1) -> B band (bf16)
#pragma unroll
  for (int nt = 0; nt < 8; ++nt) {
    int col = nt * 16 + lr;
    float bgv = bg[col], bhv = bu1[col];
#pragma unroll
    for (int rr = 0; rr < 4; ++rr) {
      float g = 1.f / (1.f + __expf(-(accG[nt][rr] + bgv)));
      accG[nt][rr] = g;
      float h = fmaxf(accH[nt][rr] + bhv, 0.f);
      B[band + lgp * 4 + rr][col] = f2bf(h);
    }
  }

  // GEMM2: upd = h1 @ Wu2
  f32x4 accU[8];
#pragma unroll
  for (int nt = 0; nt < 8; ++nt) accU[nt] = (f32x4){0.f, 0.f, 0.f, 0.f};
  {
    bf16x8 ufr[4];
#pragma unroll
    for (int kt = 0; kt < 4; ++kt)
      ufr[kt] = *reinterpret_cast<const bf16x8*>(&B[band + lr][kt * 32 + lgp * 8]);
#pragma unroll
    for (int kt = 0; kt < 4; ++kt)
#pragma unroll
      for (int nt = 0; nt < 8; ++nt)
        accU[nt] = __builtin_amdgcn_mfma_f32_16x16x32_bf16(
            ufr[kt], bfrag(Wu2, kt, nt, lane), accU[nt], 0, 0, 0);
  }

  // combine: v = gate*upd + (1-gate)*x
#pragma unroll
  for (int nt = 0; nt < 8; ++nt) {
    int col = nt * 16 + lr;
    float b2v = bu2[col];
#pragma unroll
    for (int rr = 0; rr < 4; ++rr) {
      int row = n0 + band + lgp * 4 + rr;
      float xv = (row < NN) ? x[(long)row * HH + col] : 0.f;
      float u = accU[nt][rr] + b2v;
      float g = accG[nt][rr];
      accU[nt][rr] = g * u + (1.f - g) * xv;
    }
  }

  // LayerNorm per row
#pragma unroll
  for (int rr = 0; rr < 4; ++rr) {
    int row = n0 + band + lgp * 4 + rr;
    float s = 0.f;
#pragma unroll
    for (int nt = 0; nt < 8; ++nt) s += accU[nt][rr];
    s += __shfl_xor(s, 1, 64);
    s += __shfl_xor(s, 2, 64);
    s += __shfl_xor(s, 4, 64);
    s += __shfl_xor(s, 8, 64);
    float mu = s * (1.f / 128.f);
    float qv = 0.f;
#pragma unroll
    for (int nt = 0; nt < 8; ++nt) {
      float d = accU[nt][rr] - mu;
      qv += d * d;
    }
    qv += __shfl_xor(qv, 1, 64);
    qv += __shfl_xor(qv, 2, 64);
    qv += __shfl_xor(qv, 4, 64);
    qv += __shfl_xor(qv, 8, 64);
    float rs = rsqrtf(qv * (1.f / 128.f) + 1e-5f);
    if (row < NN) {
#pragma unroll
      for (int nt = 0; nt < 8; ++nt) {
        int col = nt * 16 + lr;
        out[(long)row * HH + col] = (accU[nt][rr] - mu) * rs * gamma[col] + beta[col];
      }
    }
  }
}

extern "C" void kernel_launch(void* const* d_in, const int* in_sizes, int n_in,
                              void* d_out, int out_size, void* d_ws, size_t ws_size,
                              hipStream_t stream) {
  const float* x = (const float*)d_in[0];
  const int* ei_l = (const int*)d_in[1];
  const float* ea_l = (const float*)d_in[2];
  const int* ei_m = (const int*)d_in[3];
  const float* ea_m = (const float*)d_in[4];
  const int* ei_g = (const int*)d_in[5];
  const float* ea_g = (const float*)d_in[6];
  const float* Wa1 = (const float*)d_in[7];
  const float* ba1 = (const float*)d_in[8];
  const float* Wa2 = (const float*)d_in[9];
  const float* ba2 = (const float*)d_in[10];
  const float* Wb1 = (const float*)d_in[11];
  const float* bb1 = (const float*)d_in[12];
  const float* Wb2 = (const float*)d_in[13];
  const float* bb2 = (const float*)d_in[14];
  const float* Wc1 = (const float*)d_in[15];
  const float* bc1 = (const float*)d_in[16];
  const float* Wc2 = (const float*)d_in[17];
  const float* bc2 = (const float*)d_in[18];
  const float* Wg = (const float*)d_in[19];
  const float* bg = (const float*)d_in[20];
  const float* Wu1 = (const float*)d_in[21];
  const float* bu1 = (const float*)d_in[22];
  const float* Wu2 = (const float*)d_in[23];
  const float* bu2 = (const float*)d_in[24];
  const float* gamma = (const float*)d_in[25];
  const float* beta = (const float*)d_in[26];

  const int El = in_sizes[1] / 2;
  const int Em = in_sizes[3] / 2;
  const int Eg = in_sizes[5] / 2;
  const int Etot = El + Em + Eg;

  // Workspace layout
  float* hl = (float*)d_ws;                  // hagg local  [N][128] f32 (msg-sum pre-GEMM)
  float* hm = hl + (size_t)NN * HH;
  float* hg = hm + (size_t)NN * HH;
  unsigned short* wp = (unsigned short*)(hg + (size_t)NN * HH);
  unsigned short* W1a_a = wp; wp += 128 * 128;
  unsigned short* W1b_a = wp; wp += 128 * 128;
  unsigned short* W2_a  = wp; wp += 128 * 128;
  unsigned short* W1a_b = wp; wp += 128 * 128;
  unsigned short* W1b_b = wp; wp += 128 * 128;
  unsigned short* W2_b  = wp; wp += 128 * 128;
  unsigned short* W1a_c = wp; wp += 128 * 128;
  unsigned short* W1b_c = wp; wp += 128 * 128;
  unsigned short* W2_c  = wp; wp += 128 * 128;
  unsigned short* Wu2_s = wp; wp += 128 * 128;
  unsigned short* Wg_s  = wp; wp += 512 * 128;
  unsigned short* Wu1_s = wp; wp += 512 * 128;
  unsigned short* P_l = wp; wp += (size_t)NN * HH;
  unsigned short* Q_l = wp; wp += (size_t)NN * HH;
  unsigned short* P_m = wp; wp += (size_t)NN * HH;
  unsigned short* Q_m = wp; wp += (size_t)NN * HH;
  unsigned short* P_g = wp; wp += (size_t)NN * HH;
  unsigned short* Q_g = wp; wp += (size_t)NN * HH;
  int* ip = (int*)wp;
  int* cnt  = ip; ip += 3 * NN;   // histogram (kept -> degrees for node kernel)
  int* offs = ip; ip += 3 * NN;
  int* bsum = ip; ip += 256;
  int* ssrc = ip; ip += Etot;
  int* sdst = ip; ip += Etot;
  // align to 16B for float4
  size_t off16 = ((size_t)(ip - (int*)d_ws) * 4 + 15) & ~(size_t)15;
  float4* sea = (float4*)((char*)d_ws + off16);   // Etot float4

  hipMemsetAsync(d_ws, 0, (size_t)3 * NN * HH * sizeof(float), stream);
  hipMemsetAsync(cnt, 0, 3 * NN * sizeof(int), stream);

  // Weight swizzles
  SwzJobs jobs;
  jobs.src[0] = Wa1;            jobs.dst[0] = W1a_a;
  jobs.src[1] = Wa1 + 128*128;  jobs.dst[1] = W1b_a;
  jobs.src[2] = Wa2;            jobs.dst[2] = W2_a;
  jobs.src[3] = Wb1;            jobs.dst[3] = W1a_b;
  jobs.src[4] = Wb1 + 128*128;  jobs.dst[4] = W1b_b;
  jobs.src[5] = Wb2;            jobs.dst[5] = W2_b;
  jobs.src[6] = Wc1;            jobs.dst[6] = W1a_c;
  jobs.src[7] = Wc1 + 128*128;  jobs.dst[7] = W1b_c;
  jobs.src[8] = Wc2;            jobs.dst[8] = W2_c;
  jobs.src[9] = Wu2;            jobs.dst[9] = Wu2_s;
  jobs.src[10] = Wg;            jobs.dst[10] = Wg_s;
  jobs.src[11] = Wu1;           jobs.dst[11] = Wu1_s;
  swz_all_kernel<<<640 + 512, 256, 0, stream>>>(jobs);

  // P/Q precompute (P = x@W1a; Q = x@W1b + b1)
  PQJobs pq;
  pq.Wswz[0] = W1a_a; pq.bias[0] = nullptr; pq.out[0] = P_l;
  pq.Wswz[1] = W1b_a; pq.bias[1] = ba1;     pq.out[1] = Q_l;
  pq.Wswz[2] = W1a_b; pq.bias[2] = nullptr; pq.out[2] = P_m;
  pq.Wswz[3] = W1b_b; pq.bias[3] = bb1;     pq.out[3] = Q_m;
  pq.Wswz[4] = W1a_c; pq.bias[4] = nullptr; pq.out[4] = P_g;
  pq.Wswz[5] = W1b_c; pq.bias[5] = bc1;     pq.out[5] = Q_g;
  pq_kernel<<<(NN + 63) / 64, 256, 0, stream>>>(x, pq);

  // Counting sort by dst (materializes sorted ssrc/sdst/sea)
  hist3_kernel<<<(Etot + 255) / 256, 256, 0, stream>>>(ei_l, ei_m, ei_g, El, Em, Eg, cnt);
  const int n3 = 3 * NN;
  const int nblkA = (n3 + 1023) / 1024;
  scanA_kernel<<<nblkA, 1024, 0, stream>>>(cnt, offs, bsum, n3);
  scanB_kernel<<<1, 256, 0, stream>>>(bsum, nblkA);
  scanC_kernel<<<nblkA, 1024, 0, stream>>>(offs, bsum, n3);
  scatter3_kernel<<<(Etot + 255) / 256, 256, 0, stream>>>(
      ei_l, ei_m, ei_g, ea_l, ea_m, ea_g, El, Em, Eg, offs, ssrc, sdst, sea);

  // Edge pass: segment-summed h1 into hagg buffers (one launch, 3 scales)
  const int ntl = (El + EB - 1) / EB, ntm = (Em + EB - 1) / EB, ntg = (Eg + EB - 1) / EB;
  EParams ep;
  ep.s[0] = {ssrc,            sdst,            sea,            P_l, Q_l, Wa1 + 256 * 128, hl, El, 0};
  ep.s[1] = {ssrc + El,       sdst + El,       sea + El,       P_m, Q_m, Wb1 + 256 * 128, hm, Em, ntl};
  ep.s[2] = {ssrc + El + Em,  sdst + El + Em,  sea + El + Em,  P_g, Q_g, Wc1 + 256 * 128, hg, Eg, ntl + ntm};
  edge_kernel<<<ntl + ntm + ntg, 256, 0, stream>>>(ep);

  // Node update (fused msg GEMM via hagg@W2 + deg*b2) + LayerNorm
  node_kernel<<<(NN + 63) / 64, 256, 0, stream>>>(
      x, hl, hm, hg, cnt, W2_a, W2_b, W2_c, Wg_s, Wu1_s, Wu2_s,
      ba2, bb2, bc2, bg, bu1, bu2, gamma, beta, (float*)d_out);
}

// Round 7
// 492.543 us; speedup vs baseline: 1.2215x; 1.2215x over previous
//
#include <hip/hip_runtime.h>

typedef __attribute__((ext_vector_type(8))) short bf16x8;
typedef __attribute__((ext_vector_type(8))) unsigned short ushort8;
typedef __attribute__((ext_vector_type(4))) float f32x4;

#define NN 50000
#define HH 128
#define EB 128   // edges per block in edge kernel (32 rows per wave)

static __device__ __forceinline__ unsigned short f2bf(float f) {
  unsigned u = __builtin_bit_cast(unsigned, f);
  u = u + 0x7FFFu + ((u >> 16) & 1u);
  return (unsigned short)(u >> 16);
}

static __device__ __forceinline__ float bf2f(unsigned short b) {
  return __builtin_bit_cast(float, ((unsigned)b) << 16);
}

static __device__ __forceinline__ bf16x8 bfrag(const unsigned short* __restrict__ w,
                                               int kt, int nt, int lane) {
  return *reinterpret_cast<const bf16x8*>(w + (((kt * 8 + nt) * 64 + lane) << 3));
}

// x (fp32) -> xb (bf16), 8 elems/thread
__global__ void cvt_x_kernel(const float* __restrict__ x, unsigned short* __restrict__ xb,
                             int total8) {
  int i = blockIdx.x * 256 + threadIdx.x;
  if (i >= total8) return;
  const float4* p = reinterpret_cast<const float4*>(x + (long)i * 8);
  float4 f0 = p[0], f1 = p[1];
  ushort8 u;
  u[0] = f2bf(f0.x); u[1] = f2bf(f0.y); u[2] = f2bf(f0.z); u[3] = f2bf(f0.w);
  u[4] = f2bf(f1.x); u[5] = f2bf(f1.y); u[6] = f2bf(f1.z); u[7] = f2bf(f1.w);
  *reinterpret_cast<ushort8*>(xb + (long)i * 8) = u;
}

// Fused weight swizzle: 10 jobs with K=128 (64 blocks each), 2 jobs with K=512 (256 blocks).
struct SwzJobs {
  const float* src[12];
  unsigned short* dst[12];
};
__global__ void swz_all_kernel(SwzJobs jobs) {
  int b = blockIdx.x;
  int job, blk;
  if (b < 640) { job = b >> 6; blk = b & 63; }
  else { b -= 640; job = 10 + (b >> 8); blk = b & 255; }
  int o = blk * 256 + threadIdx.x;
  int j = o & 7, lane = (o >> 3) & 63, nt = (o >> 9) & 7, kt = o >> 12;
  int row = kt * 32 + (lane >> 4) * 8 + j;
  int col = nt * 16 + (lane & 15);
  jobs.dst[job][o] = f2bf(jobs.src[job][row * 128 + col]);
}

// P/Q precompute: 6 GEMMs out = x @ W (+bias), bf16 row-major output.
struct PQJobs {
  const unsigned short* Wswz[6];
  const float* bias[6];
  unsigned short* out[6];
};
__global__ __launch_bounds__(256) void pq_kernel(const float* __restrict__ x, PQJobs jobs) {
  __shared__ unsigned short As[64][136];
  const int t = threadIdx.x;
  const int n0 = blockIdx.x * 64;
  for (int idx = t; idx < 64 * 32; idx += 256) {
    int e = idx >> 5, c4 = (idx & 31) << 2;
    int row = n0 + e;
    float4 v = make_float4(0.f, 0.f, 0.f, 0.f);
    if (row < NN) v = *reinterpret_cast<const float4*>(x + (long)row * HH + c4);
    *reinterpret_cast<ushort4*>(&As[e][c4]) =
        make_ushort4(f2bf(v.x), f2bf(v.y), f2bf(v.z), f2bf(v.w));
  }
  __syncthreads();
  const int wave = t >> 6, lane = t & 63;
  const int lr = lane & 15, lgp = lane >> 4;
  bf16x8 afr[4];
#pragma unroll
  for (int kt = 0; kt < 4; ++kt)
    afr[kt] = *reinterpret_cast<const bf16x8*>(&As[wave * 16 + lr][kt * 32 + lgp * 8]);
#pragma unroll
  for (int jb = 0; jb < 6; ++jb) {
    f32x4 acc[8];
#pragma unroll
    for (int nt = 0; nt < 8; ++nt) acc[nt] = (f32x4){0.f, 0.f, 0.f, 0.f};
#pragma unroll
    for (int kt = 0; kt < 4; ++kt)
#pragma unroll
      for (int nt = 0; nt < 8; ++nt)
        acc[nt] = __builtin_amdgcn_mfma_f32_16x16x32_bf16(
            afr[kt], bfrag(jobs.Wswz[jb], kt, nt, lane), acc[nt], 0, 0, 0);
    const float* bi = jobs.bias[jb];
    unsigned short* O = jobs.out[jb];
#pragma unroll
    for (int nt = 0; nt < 8; ++nt) {
      int col = nt * 16 + lr;
      float bv = bi ? bi[col] : 0.f;
#pragma unroll
      for (int r = 0; r < 4; ++r) {
        int row = n0 + wave * 16 + lgp * 4 + r;
        if (row < NN) O[(long)row * HH + col] = f2bf(acc[nt][r] + bv);
      }
    }
  }
}

// ---- counting-sort by destination (two-level parallel scan) ----
__global__ void hist3_kernel(const int* __restrict__ eiL, const int* __restrict__ eiM,
                             const int* __restrict__ eiG, int El, int Em, int Eg,
                             int* __restrict__ cnt) {
  int e = blockIdx.x * 256 + threadIdx.x;
  const int* ei; int E, off;
  if (e < El) { ei = eiL; E = El; off = 0; }
  else if (e < El + Em) { e -= El; ei = eiM; E = Em; off = NN; }
  else { e -= El + Em; if (e >= Eg) return; ei = eiG; E = Eg; off = 2 * NN; }
  atomicAdd(cnt + off + ei[E + e], 1);
}

__global__ void scanA_kernel(const int* __restrict__ cnt, int* __restrict__ offs,
                             int* __restrict__ bsum, int n) {
  const int t = threadIdx.x, lane = t & 63, w = t >> 6;
  const int i = blockIdx.x * 1024 + t;
  __shared__ int wsum[16], wpre[16];
  int v = (i < n) ? cnt[i] : 0;
  int inc = v;
#pragma unroll
  for (int d = 1; d < 64; d <<= 1) {
    int o = __shfl_up(inc, d, 64);
    if (lane >= d) inc += o;
  }
  if (lane == 63) wsum[w] = inc;
  __syncthreads();
  if (t == 0) {
    int run = 0;
#pragma unroll
    for (int k = 0; k < 16; ++k) { wpre[k] = run; run += wsum[k]; }
    wsum[0] = run;
  }
  __syncthreads();
  if (i < n) offs[i] = wpre[w] + inc - v;
  if (t == 0) bsum[blockIdx.x] = wsum[0];
}

__global__ void scanB_kernel(int* __restrict__ bsum, int n) {
  const int t = threadIdx.x, lane = t & 63, w = t >> 6;
  __shared__ int wsum[4];
  int v = (t < n) ? bsum[t] : 0;
  int inc = v;
#pragma unroll
  for (int d = 1; d < 64; d <<= 1) {
    int o = __shfl_up(inc, d, 64);
    if (lane >= d) inc += o;
  }
  if (lane == 63) wsum[w] = inc;
  __syncthreads();
  int wo = 0;
  for (int k = 0; k < w; ++k) wo += wsum[k];
  if (t < n) bsum[t] = wo + inc - v;
}

__global__ void scanC_kernel(int* __restrict__ offs, const int* __restrict__ bsum, int n) {
  int i = blockIdx.x * 1024 + threadIdx.x;
  if (i < n) offs[i] += bsum[blockIdx.x];
}

// Scatter into GLOBAL sorted position: materialize sorted src/dst/edge-attr arrays.
__global__ void scatter3_kernel(const int* __restrict__ eiL, const int* __restrict__ eiM,
                                const int* __restrict__ eiG,
                                const float* __restrict__ eaL, const float* __restrict__ eaM,
                                const float* __restrict__ eaG,
                                int El, int Em, int Eg, int* __restrict__ offs,
                                int* __restrict__ ssrc, int* __restrict__ sdst,
                                float4* __restrict__ sea) {
  int e = blockIdx.x * 256 + threadIdx.x;
  const int* ei; const float* ea; int E, off;
  if (e < El) { ei = eiL; ea = eaL; E = El; off = 0; }
  else if (e < El + Em) { e -= El; ei = eiM; ea = eaM; E = Em; off = NN; }
  else { e -= El + Em; if (e >= Eg) return; ei = eiG; ea = eaG; E = Eg; off = 2 * NN; }
  int d = ei[E + e];
  int p = atomicAdd(offs + off + d, 1);
  sdst[p] = d;
  ssrc[p] = ei[e];
  sea[p] = make_float4(ea[(long)e * 3 + 0], ea[(long)e * 3 + 1], ea[(long)e * 3 + 2], 0.f);
}

// ---- edge kernel: h1 = relu(P[src]+Q[dst]+ea·Wc) summed over dst-segments,
// one atomicAdd per (unique dst, col) into hagg. No MFMA, no barriers in hot loop.
struct EScale {
  const int* ssrc; const int* sdst; const float4* sea;
  const unsigned short *P, *Q;
  const float* Wc;       // W1 rows 256..258 (3x128 fp32)
  float* hag;
  int E; int tbase;
};
struct EParams { EScale s[3]; };
__global__ __launch_bounds__(256) void edge_kernel(EParams prm) {
  __shared__ int srcs[EB], dsts[EB];
  __shared__ float eas[EB][4];
  __shared__ float Wc[384];
  const int t = threadIdx.x;

  const int nwg = gridDim.x, bid = blockIdx.x;
  const int q = nwg >> 3, r = nwg & 7;
  const int xcd = bid & 7, idx = bid >> 3;
  const int tile = (xcd < r ? xcd * (q + 1) : r * (q + 1) + (xcd - r) * q) + idx;
  const int si = (tile >= prm.s[1].tbase) + (tile >= prm.s[2].tbase);
  const EScale S = prm.s[si];
  const int e0 = (tile - S.tbase) * EB;

  if (t < EB) {
    int ge = e0 + t;
    int d = -1, s = 0;
    float4 e4 = make_float4(0.f, 0.f, 0.f, 0.f);
    if (ge < S.E) { d = S.sdst[ge]; s = S.ssrc[ge]; e4 = S.sea[ge]; }
    dsts[t] = d; srcs[t] = s;
    *reinterpret_cast<float4*>(&eas[t][0]) = e4;
  }
  for (int i = t; i < 384; i += 256) Wc[i] = S.Wc[i];
  __syncthreads();

  const int wave = t >> 6, lane = t & 63;
  const int c2 = lane * 2;
  const float wcA0 = Wc[c2], wcB0 = Wc[c2 + 1];
  const float wcA1 = Wc[128 + c2], wcB1 = Wc[129 + c2];
  const float wcA2 = Wc[256 + c2], wcB2 = Wc[257 + c2];
  const int r0 = wave * 32;

  int cur = -1;
  float aA = 0.f, aB = 0.f, qA = 0.f, qB = 0.f;
  for (int rr = 0; rr < 32; ++rr) {
    int rI = r0 + rr;
    int d = dsts[rI];
    if (d != cur) {
      if (cur >= 0) {
        atomicAdd(S.hag + (long)cur * HH + c2, aA);
        atomicAdd(S.hag + (long)cur * HH + c2 + 1, aB);
      }
      cur = d; aA = aB = 0.f;
      if (d < 0) break;
      ushort2 qv = *reinterpret_cast<const ushort2*>(S.Q + (long)d * HH + c2);
      qA = bf2f(qv.x); qB = bf2f(qv.y);
    }
    int sN = srcs[rI];
    float e0v = eas[rI][0], e1v = eas[rI][1], e2v = eas[rI][2];
    ushort2 p = *reinterpret_cast<const ushort2*>(S.P + (long)sN * HH + c2);
    float vA = bf2f(p.x) + qA + e0v * wcA0 + e1v * wcA1 + e2v * wcA2;
    float vB = bf2f(p.y) + qB + e0v * wcB0 + e1v * wcB1 + e2v * wcB2;
    aA += fmaxf(vA, 0.f);
    aB += fmaxf(vB, 0.f);
  }
  if (cur >= 0) {
    atomicAdd(S.hag + (long)cur * HH + c2, aA);
    atomicAdd(S.hag + (long)cur * HH + c2 + 1, aB);
  }
}

// ---- msg kernel: M_s = bf16(hagg_s @ W2_s + deg_s*b2_s), one scale-tile per block ----
struct MsgScale {
  const float* H; const unsigned short* W2s; const float* b2; const int* deg;
  unsigned short* M;
};
struct MsgParams { MsgScale s[3]; };
__global__ __launch_bounds__(256) void msg_kernel(MsgParams prm) {
  __shared__ unsigned short As[64][136];
  const int bid = blockIdx.x;
  const int si = bid % 3;
  const int n0 = (bid / 3) * 64;
  const MsgScale S = prm.s[si];
  const int t = threadIdx.x;
  for (int idx = t; idx < 64 * 32; idx += 256) {
    int e = idx >> 5, c4 = (idx & 31) << 2;
    int row = n0 + e;
    float4 v = make_float4(0.f, 0.f, 0.f, 0.f);
    if (row < NN) v = *reinterpret_cast<const float4*>(S.H + (long)row * HH + c4);
    *reinterpret_cast<ushort4*>(&As[e][c4]) =
        make_ushort4(f2bf(v.x), f2bf(v.y), f2bf(v.z), f2bf(v.w));
  }
  __syncthreads();
  const int wave = t >> 6, lane = t & 63;
  const int lr = lane & 15, lgp = lane >> 4;
  bf16x8 afr[4];
#pragma unroll
  for (int kt = 0; kt < 4; ++kt)
    afr[kt] = *reinterpret_cast<const bf16x8*>(&As[wave * 16 + lr][kt * 32 + lgp * 8]);
  f32x4 acc[8];
#pragma unroll
  for (int nt = 0; nt < 8; ++nt) acc[nt] = (f32x4){0.f, 0.f, 0.f, 0.f};
#pragma unroll
  for (int kt = 0; kt < 4; ++kt)
#pragma unroll
    for (int nt = 0; nt < 8; ++nt)
      acc[nt] = __builtin_amdgcn_mfma_f32_16x16x32_bf16(
          afr[kt], bfrag(S.W2s, kt, nt, lane), acc[nt], 0, 0, 0);
#pragma unroll
  for (int nt = 0; nt < 8; ++nt) {
    int col = nt * 16 + lr;
    float bv = S.b2[col];
#pragma unroll
    for (int r = 0; r < 4; ++r) {
      int row = n0 + wave * 16 + lgp * 4 + r;
      if (row < NN) {
        float dg = (float)S.deg[row];
        S.M[(long)row * HH + col] = f2bf(acc[nt][r] + dg * bv);
      }
    }
  }
}

// ---- node kernel: streaming K=512 over bf16 [xb|Ml|Mm|Mg], two GEMMs + Wu2 + LN ----
__global__ __launch_bounds__(256) void node_kernel(
    const float* __restrict__ x, const unsigned short* __restrict__ xb,
    const unsigned short* __restrict__ Ml, const unsigned short* __restrict__ Mm,
    const unsigned short* __restrict__ Mg,
    const unsigned short* __restrict__ Wg, const unsigned short* __restrict__ Wu1,
    const unsigned short* __restrict__ Wu2,
    const float* __restrict__ bg, const float* __restrict__ bu1, const float* __restrict__ bu2,
    const float* __restrict__ gamma, const float* __restrict__ beta,
    float* __restrict__ out) {
  __shared__ unsigned short Hs[64][136];
  const int t = threadIdx.x;
  const int n0 = blockIdx.x * 64;
  const int wave = t >> 6, lane = t & 63;
  const int lr = lane & 15, lgp = lane >> 4;

  f32x4 accG[8], accH[8];
#pragma unroll
  for (int nt = 0; nt < 8; ++nt) {
    accG[nt] = (f32x4){0.f, 0.f, 0.f, 0.f};
    accH[nt] = (f32x4){0.f, 0.f, 0.f, 0.f};
  }
  const int arow = n0 + wave * 16 + lr;
  const bool aok = arow < NN;

#pragma unroll
  for (int kt = 0; kt < 16; ++kt) {
    const unsigned short* S = (kt < 4) ? xb : (kt < 8) ? Ml : (kt < 12) ? Mm : Mg;
    int cb = ((kt & 3) << 5) + (lgp << 3);
    bf16x8 a = (bf16x8){0, 0, 0, 0, 0, 0, 0, 0};
    if (aok) a = *reinterpret_cast<const bf16x8*>(S + (long)arow * HH + cb);
#pragma unroll
    for (int nt = 0; nt < 8; ++nt) {
      accG[nt] = __builtin_amdgcn_mfma_f32_16x16x32_bf16(a, bfrag(Wg, kt, nt, lane), accG[nt], 0, 0, 0);
      accH[nt] = __builtin_amdgcn_mfma_f32_16x16x32_bf16(a, bfrag(Wu1, kt, nt, lane), accH[nt], 0, 0, 0);
    }
  }

#pragma unroll
  for (int nt = 0; nt < 8; ++nt) {
    int col = nt * 16 + lr;
    float bgv = bg[col], bhv = bu1[col];
#pragma unroll
    for (int r = 0; r < 4; ++r) {
      float g = 1.f / (1.f + __expf(-(accG[nt][r] + bgv)));
      accG[nt][r] = g;
      float h = fmaxf(accH[nt][r] + bhv, 0.f);
      Hs[wave * 16 + lgp * 4 + r][col] = f2bf(h);
    }
  }

  f32x4 accU[8];
#pragma unroll
  for (int nt = 0; nt < 8; ++nt) accU[nt] = (f32x4){0.f, 0.f, 0.f, 0.f};
#pragma unroll
  for (int kt = 0; kt < 4; ++kt) {
    bf16x8 a = *reinterpret_cast<const bf16x8*>(&Hs[wave * 16 + lr][kt * 32 + lgp * 8]);
#pragma unroll
    for (int nt = 0; nt < 8; ++nt) {
      accU[nt] = __builtin_amdgcn_mfma_f32_16x16x32_bf16(a, bfrag(Wu2, kt, nt, lane), accU[nt], 0, 0, 0);
    }
  }

#pragma unroll
  for (int nt = 0; nt < 8; ++nt) {
    int col = nt * 16 + lr;
    float b2v = bu2[col];
#pragma unroll
    for (int r = 0; r < 4; ++r) {
      int row = n0 + wave * 16 + lgp * 4 + r;
      float xv = (row < NN) ? x[(long)row * HH + col] : 0.f;
      float u = accU[nt][r] + b2v;
      float g = accG[nt][r];
      accU[nt][r] = g * u + (1.f - g) * xv;
    }
  }

#pragma unroll
  for (int r = 0; r < 4; ++r) {
    int row = n0 + wave * 16 + lgp * 4 + r;
    float s = 0.f;
#pragma unroll
    for (int nt = 0; nt < 8; ++nt) s += accU[nt][r];
    s += __shfl_xor(s, 1, 64);
    s += __shfl_xor(s, 2, 64);
    s += __shfl_xor(s, 4, 64);
    s += __shfl_xor(s, 8, 64);
    float mu = s * (1.f / 128.f);
    float qv = 0.f;
#pragma unroll
    for (int nt = 0; nt < 8; ++nt) {
      float d = accU[nt][r] - mu;
      qv += d * d;
    }
    qv += __shfl_xor(qv, 1, 64);
    qv += __shfl_xor(qv, 2, 64);
    qv += __shfl_xor(qv, 4, 64);
    qv += __shfl_xor(qv, 8, 64);
    float rs = rsqrtf(qv * (1.f / 128.f) + 1e-5f);
    if (row < NN) {
#pragma unroll
      for (int nt = 0; nt < 8; ++nt) {
        int col = nt * 16 + lr;
        out[(long)row * HH + col] = (accU[nt][r] - mu) * rs * gamma[col] + beta[col];
      }
    }
  }
}

extern "C" void kernel_launch(void* const* d_in, const int* in_sizes, int n_in,
                              void* d_out, int out_size, void* d_ws, size_t ws_size,
                              hipStream_t stream) {
  const float* x = (const float*)d_in[0];
  const int* ei_l = (const int*)d_in[1];
  const float* ea_l = (const float*)d_in[2];
  const int* ei_m = (const int*)d_in[3];
  const float* ea_m = (const float*)d_in[4];
  const int* ei_g = (const int*)d_in[5];
  const float* ea_g = (const float*)d_in[6];
  const float* Wa1 = (const float*)d_in[7];
  const float* ba1 = (const float*)d_in[8];
  const float* Wa2 = (const float*)d_in[9];
  const float* ba2 = (const float*)d_in[10];
  const float* Wb1 = (const float*)d_in[11];
  const float* bb1 = (const float*)d_in[12];
  const float* Wb2 = (const float*)d_in[13];
  const float* bb2 = (const float*)d_in[14];
  const float* Wc1 = (const float*)d_in[15];
  const float* bc1 = (const float*)d_in[16];
  const float* Wc2 = (const float*)d_in[17];
  const float* bc2 = (const float*)d_in[18];
  const float* Wg = (const float*)d_in[19];
  const float* bg = (const float*)d_in[20];
  const float* Wu1 = (const float*)d_in[21];
  const float* bu1 = (const float*)d_in[22];
  const float* Wu2 = (const float*)d_in[23];
  const float* bu2 = (const float*)d_in[24];
  const float* gamma = (const float*)d_in[25];
  const float* beta = (const float*)d_in[26];

  const int El = in_sizes[1] / 2;
  const int Em = in_sizes[3] / 2;
  const int Eg = in_sizes[5] / 2;
  const int Etot = El + Em + Eg;

  // Workspace layout
  float* hl = (float*)d_ws;                  // hagg [N][128] f32 per scale
  float* hm = hl + (size_t)NN * HH;
  float* hg = hm + (size_t)NN * HH;
  unsigned short* wp = (unsigned short*)(hg + (size_t)NN * HH);
  unsigned short* W1a_a = wp; wp += 128 * 128;
  unsigned short* W1b_a = wp; wp += 128 * 128;
  unsigned short* W2_a  = wp; wp += 128 * 128;
  unsigned short* W1a_b = wp; wp += 128 * 128;
  unsigned short* W1b_b = wp; wp += 128 * 128;
  unsigned short* W2_b  = wp; wp += 128 * 128;
  unsigned short* W1a_c = wp; wp += 128 * 128;
  unsigned short* W1b_c = wp; wp += 128 * 128;
  unsigned short* W2_c  = wp; wp += 128 * 128;
  unsigned short* Wu2_s = wp; wp += 128 * 128;
  unsigned short* Wg_s  = wp; wp += 512 * 128;
  unsigned short* Wu1_s = wp; wp += 512 * 128;
  unsigned short* xb  = wp; wp += (size_t)NN * HH;
  unsigned short* P_l = wp; wp += (size_t)NN * HH;
  unsigned short* Q_l = wp; wp += (size_t)NN * HH;
  unsigned short* P_m = wp; wp += (size_t)NN * HH;
  unsigned short* Q_m = wp; wp += (size_t)NN * HH;
  unsigned short* P_g = wp; wp += (size_t)NN * HH;
  unsigned short* Q_g = wp; wp += (size_t)NN * HH;
  // M buffers alias the P buffers (P dead after edge_kernel; stream order guarantees safety)
  unsigned short* M_l = P_l;
  unsigned short* M_m = P_m;
  unsigned short* M_g = P_g;
  int* ip = (int*)wp;
  int* cnt  = ip; ip += 3 * NN;   // histogram (kept -> degrees for msg kernel)
  int* offs = ip; ip += 3 * NN;
  int* bsum = ip; ip += 256;
  int* ssrc = ip; ip += Etot;
  int* sdst = ip; ip += Etot;
  size_t off16 = ((size_t)((char*)ip - (char*)d_ws) + 15) & ~(size_t)15;
  float4* sea = (float4*)((char*)d_ws + off16);   // Etot float4

  hipMemsetAsync(d_ws, 0, (size_t)3 * NN * HH * sizeof(float), stream);
  hipMemsetAsync(cnt, 0, 3 * NN * sizeof(int), stream);

  // x -> bf16
  cvt_x_kernel<<<(NN * HH / 8 + 255) / 256, 256, 0, stream>>>(x, xb, NN * HH / 8);

  // Weight swizzles
  SwzJobs jobs;
  jobs.src[0] = Wa1;            jobs.dst[0] = W1a_a;
  jobs.src[1] = Wa1 + 128*128;  jobs.dst[1] = W1b_a;
  jobs.src[2] = Wa2;            jobs.dst[2] = W2_a;
  jobs.src[3] = Wb1;            jobs.dst[3] = W1a_b;
  jobs.src[4] = Wb1 + 128*128;  jobs.dst[4] = W1b_b;
  jobs.src[5] = Wb2;            jobs.dst[5] = W2_b;
  jobs.src[6] = Wc1;            jobs.dst[6] = W1a_c;
  jobs.src[7] = Wc1 + 128*128;  jobs.dst[7] = W1b_c;
  jobs.src[8] = Wc2;            jobs.dst[8] = W2_c;
  jobs.src[9] = Wu2;            jobs.dst[9] = Wu2_s;
  jobs.src[10] = Wg;            jobs.dst[10] = Wg_s;
  jobs.src[11] = Wu1;           jobs.dst[11] = Wu1_s;
  swz_all_kernel<<<640 + 512, 256, 0, stream>>>(jobs);

  // P/Q precompute (P = x@W1a; Q = x@W1b + b1)
  PQJobs pq;
  pq.Wswz[0] = W1a_a; pq.bias[0] = nullptr; pq.out[0] = P_l;
  pq.Wswz[1] = W1b_a; pq.bias[1] = ba1;     pq.out[1] = Q_l;
  pq.Wswz[2] = W1a_b; pq.bias[2] = nullptr; pq.out[2] = P_m;
  pq.Wswz[3] = W1b_b; pq.bias[3] = bb1;     pq.out[3] = Q_m;
  pq.Wswz[4] = W1a_c; pq.bias[4] = nullptr; pq.out[4] = P_g;
  pq.Wswz[5] = W1b_c; pq.bias[5] = bc1;     pq.out[5] = Q_g;
  pq_kernel<<<(NN + 63) / 64, 256, 0, stream>>>(x, pq);

  // Counting sort by dst (materializes sorted ssrc/sdst/sea)
  hist3_kernel<<<(Etot + 255) / 256, 256, 0, stream>>>(ei_l, ei_m, ei_g, El, Em, Eg, cnt);
  const int n3 = 3 * NN;
  const int nblkA = (n3 + 1023) / 1024;
  scanA_kernel<<<nblkA, 1024, 0, stream>>>(cnt, offs, bsum, n3);
  scanB_kernel<<<1, 256, 0, stream>>>(bsum, nblkA);
  scanC_kernel<<<nblkA, 1024, 0, stream>>>(offs, bsum, n3);
  scatter3_kernel<<<(Etot + 255) / 256, 256, 0, stream>>>(
      ei_l, ei_m, ei_g, ea_l, ea_m, ea_g, El, Em, Eg, offs, ssrc, sdst, sea);

  // Edge pass: segment-summed h1 into hagg buffers (one launch, 3 scales)
  const int ntl = (El + EB - 1) / EB, ntm = (Em + EB - 1) / EB, ntg = (Eg + EB - 1) / EB;
  EParams ep;
  ep.s[0] = {ssrc,           sdst,           sea,           P_l, Q_l, Wa1 + 256 * 128, hl, El, 0};
  ep.s[1] = {ssrc + El,      sdst + El,      sea + El,      P_m, Q_m, Wb1 + 256 * 128, hm, Em, ntl};
  ep.s[2] = {ssrc + El + Em, sdst + El + Em, sea + El + Em, P_g, Q_g, Wc1 + 256 * 128, hg, Eg, ntl + ntm};
  edge_kernel<<<ntl + ntm + ntg, 256, 0, stream>>>(ep);

  // Msg pass: M_s = bf16(hagg_s @ W2_s + deg*b2_s)
  MsgParams mp;
  mp.s[0] = {hl, W2_a, ba2, cnt,          M_l};
  mp.s[1] = {hm, W2_b, bb2, cnt + NN,     M_m};
  mp.s[2] = {hg, W2_c, bc2, cnt + 2 * NN, M_g};
  const int NB = (NN + 63) / 64;
  msg_kernel<<<3 * NB, 256, 0, stream>>>(mp);

  // Node update + LayerNorm (all-bf16 A-stream)
  node_kernel<<<NB, 256, 0, stream>>>(x, xb, M_l, M_m, M_g, Wg_s, Wu1_s, Wu2_s,
                                      bg, bu1, bu2, gamma, beta, (float*)d_out);
}

// Round 8
// 479.929 us; speedup vs baseline: 1.2537x; 1.0263x over previous
//
#include <hip/hip_runtime.h>

typedef __attribute__((ext_vector_type(8))) short bf16x8;
typedef __attribute__((ext_vector_type(8))) unsigned short ushort8;
typedef __attribute__((ext_vector_type(4))) float f32x4;

#define NN 50000
#define HH 128
#define EB 128   // edges per block in edge kernel (32 rows per wave)

static __device__ __forceinline__ unsigned short f2bf(float f) {
  unsigned u = __builtin_bit_cast(unsigned, f);
  u = u + 0x7FFFu + ((u >> 16) & 1u);
  return (unsigned short)(u >> 16);
}

static __device__ __forceinline__ float bf2f(unsigned short b) {
  return __builtin_bit_cast(float, ((unsigned)b) << 16);
}

static __device__ __forceinline__ bf16x8 bfrag(const unsigned short* __restrict__ w,
                                               int kt, int nt, int lane) {
  return *reinterpret_cast<const bf16x8*>(w + (((kt * 8 + nt) * 64 + lane) << 3));
}

// Fused weight swizzle: 10 jobs with K=128 (64 blocks each), 2 jobs with K=512 (256 blocks).
struct SwzJobs {
  const float* src[12];
  unsigned short* dst[12];
};
__global__ void swz_all_kernel(SwzJobs jobs) {
  int b = blockIdx.x;
  int job, blk;
  if (b < 640) { job = b >> 6; blk = b & 63; }
  else { b -= 640; job = 10 + (b >> 8); blk = b & 255; }
  int o = blk * 256 + threadIdx.x;
  int j = o & 7, lane = (o >> 3) & 63, nt = (o >> 9) & 7, kt = o >> 12;
  int row = kt * 32 + (lane >> 4) * 8 + j;
  int col = nt * 16 + (lane & 15);
  jobs.dst[job][o] = f2bf(jobs.src[job][row * 128 + col]);
}

// P/Q precompute: 6 GEMMs out = x @ W (+bias), bf16 row-major output.
// Also writes the staged bf16 x rows out as xb (saves a separate cvt kernel).
struct PQJobs {
  const unsigned short* Wswz[6];
  const float* bias[6];
  unsigned short* out[6];
};
__global__ __launch_bounds__(256) void pq_kernel(const float* __restrict__ x,
                                                 unsigned short* __restrict__ xb,
                                                 PQJobs jobs) {
  __shared__ unsigned short As[64][136];
  const int t = threadIdx.x;
  const int n0 = blockIdx.x * 64;
  for (int idx = t; idx < 64 * 32; idx += 256) {
    int e = idx >> 5, c4 = (idx & 31) << 2;
    int row = n0 + e;
    float4 v = make_float4(0.f, 0.f, 0.f, 0.f);
    if (row < NN) v = *reinterpret_cast<const float4*>(x + (long)row * HH + c4);
    *reinterpret_cast<ushort4*>(&As[e][c4]) =
        make_ushort4(f2bf(v.x), f2bf(v.y), f2bf(v.z), f2bf(v.w));
  }
  __syncthreads();
  // write xb (coalesced ushort4 stores)
  for (int idx = t; idx < 64 * 32; idx += 256) {
    int e = idx >> 5, c4 = (idx & 31) << 2;
    int row = n0 + e;
    if (row < NN)
      *reinterpret_cast<ushort4*>(xb + (long)row * HH + c4) =
          *reinterpret_cast<const ushort4*>(&As[e][c4]);
  }
  const int wave = t >> 6, lane = t & 63;
  const int lr = lane & 15, lgp = lane >> 4;
  bf16x8 afr[4];
#pragma unroll
  for (int kt = 0; kt < 4; ++kt)
    afr[kt] = *reinterpret_cast<const bf16x8*>(&As[wave * 16 + lr][kt * 32 + lgp * 8]);
#pragma unroll
  for (int jb = 0; jb < 6; ++jb) {
    f32x4 acc[8];
#pragma unroll
    for (int nt = 0; nt < 8; ++nt) acc[nt] = (f32x4){0.f, 0.f, 0.f, 0.f};
#pragma unroll
    for (int kt = 0; kt < 4; ++kt)
#pragma unroll
      for (int nt = 0; nt < 8; ++nt)
        acc[nt] = __builtin_amdgcn_mfma_f32_16x16x32_bf16(
            afr[kt], bfrag(jobs.Wswz[jb], kt, nt, lane), acc[nt], 0, 0, 0);
    const float* bi = jobs.bias[jb];
    unsigned short* O = jobs.out[jb];
#pragma unroll
    for (int nt = 0; nt < 8; ++nt) {
      int col = nt * 16 + lr;
      float bv = bi ? bi[col] : 0.f;
#pragma unroll
      for (int r = 0; r < 4; ++r) {
        int row = n0 + wave * 16 + lgp * 4 + r;
        if (row < NN) O[(long)row * HH + col] = f2bf(acc[nt][r] + bv);
      }
    }
  }
}

// ---- counting-sort by destination (two-level parallel scan) ----
__global__ void hist3_kernel(const int* __restrict__ eiL, const int* __restrict__ eiM,
                             const int* __restrict__ eiG, int El, int Em, int Eg,
                             int* __restrict__ cnt) {
  int e = blockIdx.x * 256 + threadIdx.x;
  const int* ei; int E, off;
  if (e < El) { ei = eiL; E = El; off = 0; }
  else if (e < El + Em) { e -= El; ei = eiM; E = Em; off = NN; }
  else { e -= El + Em; if (e >= Eg) return; ei = eiG; E = Eg; off = 2 * NN; }
  atomicAdd(cnt + off + ei[E + e], 1);
}

__global__ void scanA_kernel(const int* __restrict__ cnt, int* __restrict__ offs,
                             int* __restrict__ bsum, int n) {
  const int t = threadIdx.x, lane = t & 63, w = t >> 6;
  const int i = blockIdx.x * 1024 + t;
  __shared__ int wsum[16], wpre[16];
  int v = (i < n) ? cnt[i] : 0;
  int inc = v;
#pragma unroll
  for (int d = 1; d < 64; d <<= 1) {
    int o = __shfl_up(inc, d, 64);
    if (lane >= d) inc += o;
  }
  if (lane == 63) wsum[w] = inc;
  __syncthreads();
  if (t == 0) {
    int run = 0;
#pragma unroll
    for (int k = 0; k < 16; ++k) { wpre[k] = run; run += wsum[k]; }
    wsum[0] = run;
  }
  __syncthreads();
  if (i < n) offs[i] = wpre[w] + inc - v;
  if (t == 0) bsum[blockIdx.x] = wsum[0];
}

__global__ void scanB_kernel(int* __restrict__ bsum, int n) {
  const int t = threadIdx.x, lane = t & 63, w = t >> 6;
  __shared__ int wsum[4];
  int v = (t < n) ? bsum[t] : 0;
  int inc = v;
#pragma unroll
  for (int d = 1; d < 64; d <<= 1) {
    int o = __shfl_up(inc, d, 64);
    if (lane >= d) inc += o;
  }
  if (lane == 63) wsum[w] = inc;
  __syncthreads();
  int wo = 0;
  for (int k = 0; k < w; ++k) wo += wsum[k];
  if (t < n) bsum[t] = wo + inc - v;
}

__global__ void scanC_kernel(int* __restrict__ offs, const int* __restrict__ bsum, int n) {
  int i = blockIdx.x * 1024 + threadIdx.x;
  if (i < n) offs[i] += bsum[blockIdx.x];
}

// Scatter into GLOBAL sorted position: materialize sorted src/dst/edge-attr arrays.
__global__ void scatter3_kernel(const int* __restrict__ eiL, const int* __restrict__ eiM,
                                const int* __restrict__ eiG,
                                const float* __restrict__ eaL, const float* __restrict__ eaM,
                                const float* __restrict__ eaG,
                                int El, int Em, int Eg, int* __restrict__ offs,
                                int* __restrict__ ssrc, int* __restrict__ sdst,
                                float4* __restrict__ sea) {
  int e = blockIdx.x * 256 + threadIdx.x;
  const int* ei; const float* ea; int E, off;
  if (e < El) { ei = eiL; ea = eaL; E = El; off = 0; }
  else if (e < El + Em) { e -= El; ei = eiM; ea = eaM; E = Em; off = NN; }
  else { e -= El + Em; if (e >= Eg) return; ei = eiG; ea = eaG; E = Eg; off = 2 * NN; }
  int d = ei[E + e];
  int p = atomicAdd(offs + off + d, 1);
  sdst[p] = d;
  ssrc[p] = ei[e];
  sea[p] = make_float4(ea[(long)e * 3 + 0], ea[(long)e * 3 + 1], ea[(long)e * 3 + 2], 0.f);
}

// ---- edge kernel: h1 = relu(P[src]+Q[dst]+ea·Wc) summed over dst-segments,
// one atomicAdd per (unique dst, col) into hagg. All 32 P-gathers prefetched
// into registers up front (MLP); segment logic is wave-uniform scalar.
struct EScale {
  const int* ssrc; const int* sdst; const float4* sea;
  const unsigned short *P, *Q;
  const float* Wc;       // W1 rows 256..258 (3x128 fp32)
  float* hag;
  int E; int tbase;
};
struct EParams { EScale s[3]; };
__global__ __launch_bounds__(256) void edge_kernel(EParams prm) {
  __shared__ int srcs[EB], dsts[EB];
  __shared__ float eas[EB][4];
  __shared__ float Wc[384];
  const int t = threadIdx.x;

  const int nwg = gridDim.x, bid = blockIdx.x;
  const int q = nwg >> 3, r = nwg & 7;
  const int xcd = bid & 7, idx = bid >> 3;
  const int tile = (xcd < r ? xcd * (q + 1) : r * (q + 1) + (xcd - r) * q) + idx;
  const int si = (tile >= prm.s[1].tbase) + (tile >= prm.s[2].tbase);
  const EScale S = prm.s[si];
  const int e0 = (tile - S.tbase) * EB;

  if (t < EB) {
    int ge = e0 + t;
    int d = -1, s = 0;
    float4 e4 = make_float4(0.f, 0.f, 0.f, 0.f);
    if (ge < S.E) { d = S.sdst[ge]; s = S.ssrc[ge]; e4 = S.sea[ge]; }
    dsts[t] = d; srcs[t] = s;
    *reinterpret_cast<float4*>(&eas[t][0]) = e4;
  }
  for (int i = t; i < 384; i += 256) Wc[i] = S.Wc[i];
  __syncthreads();

  const int wave = t >> 6, lane = t & 63;
  const int c2 = lane * 2;
  const float wcA0 = Wc[c2], wcB0 = Wc[c2 + 1];
  const float wcA1 = Wc[128 + c2], wcB1 = Wc[129 + c2];
  const float wcA2 = Wc[256 + c2], wcB2 = Wc[257 + c2];
  const int r0 = wave * 32;

  // Prefetch: issue all 32 P-row gathers before consuming any (32 loads in flight).
  ushort2 pb[32];
#pragma unroll
  for (int rr = 0; rr < 32; ++rr) {
    int sN = srcs[r0 + rr];
    pb[rr] = *reinterpret_cast<const ushort2*>(S.P + (long)sN * HH + c2);
  }

  int cur = -1;
  float aA = 0.f, aB = 0.f, qA = 0.f, qB = 0.f;
#pragma unroll
  for (int rr = 0; rr < 32; ++rr) {
    int rI = r0 + rr;
    int d = dsts[rI];
    if (d != cur) {
      if (cur >= 0) {
        atomicAdd(S.hag + (long)cur * HH + c2, aA);
        atomicAdd(S.hag + (long)cur * HH + c2 + 1, aB);
      }
      cur = d; aA = aB = 0.f;
      if (d < 0) break;
      ushort2 qv = *reinterpret_cast<const ushort2*>(S.Q + (long)d * HH + c2);
      qA = bf2f(qv.x); qB = bf2f(qv.y);
    }
    float e0v = eas[rI][0], e1v = eas[rI][1], e2v = eas[rI][2];
    float vA = bf2f(pb[rr].x) + qA + e0v * wcA0 + e1v * wcA1 + e2v * wcA2;
    float vB = bf2f(pb[rr].y) + qB + e0v * wcB0 + e1v * wcB1 + e2v * wcB2;
    aA += fmaxf(vA, 0.f);
    aB += fmaxf(vB, 0.f);
  }
  if (cur >= 0) {
    atomicAdd(S.hag + (long)cur * HH + c2, aA);
    atomicAdd(S.hag + (long)cur * HH + c2 + 1, aB);
  }
}

// ---- msg kernel: M_s = bf16(hagg_s @ W2_s + deg_s*b2_s), one scale-tile per block ----
struct MsgScale {
  const float* H; const unsigned short* W2s; const float* b2; const int* deg;
  unsigned short* M;
};
struct MsgParams { MsgScale s[3]; };
__global__ __launch_bounds__(256) void msg_kernel(MsgParams prm) {
  __shared__ unsigned short As[64][136];
  const int bid = blockIdx.x;
  const int si = bid % 3;
  const int n0 = (bid / 3) * 64;
  const MsgScale S = prm.s[si];
  const int t = threadIdx.x;
  for (int idx = t; idx < 64 * 32; idx += 256) {
    int e = idx >> 5, c4 = (idx & 31) << 2;
    int row = n0 + e;
    float4 v = make_float4(0.f, 0.f, 0.f, 0.f);
    if (row < NN) v = *reinterpret_cast<const float4*>(S.H + (long)row * HH + c4);
    *reinterpret_cast<ushort4*>(&As[e][c4]) =
        make_ushort4(f2bf(v.x), f2bf(v.y), f2bf(v.z), f2bf(v.w));
  }
  __syncthreads();
  const int wave = t >> 6, lane = t & 63;
  const int lr = lane & 15, lgp = lane >> 4;
  bf16x8 afr[4];
#pragma unroll
  for (int kt = 0; kt < 4; ++kt)
    afr[kt] = *reinterpret_cast<const bf16x8*>(&As[wave * 16 + lr][kt * 32 + lgp * 8]);
  f32x4 acc[8];
#pragma unroll
  for (int nt = 0; nt < 8; ++nt) acc[nt] = (f32x4){0.f, 0.f, 0.f, 0.f};
#pragma unroll
  for (int kt = 0; kt < 4; ++kt)
#pragma unroll
    for (int nt = 0; nt < 8; ++nt)
      acc[nt] = __builtin_amdgcn_mfma_f32_16x16x32_bf16(
          afr[kt], bfrag(S.W2s, kt, nt, lane), acc[nt], 0, 0, 0);
#pragma unroll
  for (int nt = 0; nt < 8; ++nt) {
    int col = nt * 16 + lr;
    float bv = S.b2[col];
#pragma unroll
    for (int r = 0; r < 4; ++r) {
      int row = n0 + wave * 16 + lgp * 4 + r;
      if (row < NN) {
        float dg = (float)S.deg[row];
        S.M[(long)row * HH + col] = f2bf(acc[nt][r] + dg * bv);
      }
    }
  }
}

// ---- node kernel: streaming K=512 over bf16 [xb|Ml|Mm|Mg], two GEMMs + Wu2 + LN ----
__global__ __launch_bounds__(256) void node_kernel(
    const float* __restrict__ x, const unsigned short* __restrict__ xb,
    const unsigned short* __restrict__ Ml, const unsigned short* __restrict__ Mm,
    const unsigned short* __restrict__ Mg,
    const unsigned short* __restrict__ Wg, const unsigned short* __restrict__ Wu1,
    const unsigned short* __restrict__ Wu2,
    const float* __restrict__ bg, const float* __restrict__ bu1, const float* __restrict__ bu2,
    const float* __restrict__ gamma, const float* __restrict__ beta,
    float* __restrict__ out) {
  __shared__ unsigned short Hs[64][136];
  const int t = threadIdx.x;
  const int n0 = blockIdx.x * 64;
  const int wave = t >> 6, lane = t & 63;
  const int lr = lane & 15, lgp = lane >> 4;

  f32x4 accG[8], accH[8];
#pragma unroll
  for (int nt = 0; nt < 8; ++nt) {
    accG[nt] = (f32x4){0.f, 0.f, 0.f, 0.f};
    accH[nt] = (f32x4){0.f, 0.f, 0.f, 0.f};
  }
  const int arow = n0 + wave * 16 + lr;
  const bool aok = arow < NN;

#pragma unroll
  for (int kt = 0; kt < 16; ++kt) {
    const unsigned short* S = (kt < 4) ? xb : (kt < 8) ? Ml : (kt < 12) ? Mm : Mg;
    int cb = ((kt & 3) << 5) + (lgp << 3);
    bf16x8 a = (bf16x8){0, 0, 0, 0, 0, 0, 0, 0};
    if (aok) a = *reinterpret_cast<const bf16x8*>(S + (long)arow * HH + cb);
#pragma unroll
    for (int nt = 0; nt < 8; ++nt) {
      accG[nt] = __builtin_amdgcn_mfma_f32_16x16x32_bf16(a, bfrag(Wg, kt, nt, lane), accG[nt], 0, 0, 0);
      accH[nt] = __builtin_amdgcn_mfma_f32_16x16x32_bf16(a, bfrag(Wu1, kt, nt, lane), accH[nt], 0, 0, 0);
    }
  }

#pragma unroll
  for (int nt = 0; nt < 8; ++nt) {
    int col = nt * 16 + lr;
    float bgv = bg[col], bhv = bu1[col];
#pragma unroll
    for (int r = 0; r < 4; ++r) {
      float g = 1.f / (1.f + __expf(-(accG[nt][r] + bgv)));
      accG[nt][r] = g;
      float h = fmaxf(accH[nt][r] + bhv, 0.f);
      Hs[wave * 16 + lgp * 4 + r][col] = f2bf(h);
    }
  }

  f32x4 accU[8];
#pragma unroll
  for (int nt = 0; nt < 8; ++nt) accU[nt] = (f32x4){0.f, 0.f, 0.f, 0.f};
#pragma unroll
  for (int kt = 0; kt < 4; ++kt) {
    bf16x8 a = *reinterpret_cast<const bf16x8*>(&Hs[wave * 16 + lr][kt * 32 + lgp * 8]);
#pragma unroll
    for (int nt = 0; nt < 8; ++nt) {
      accU[nt] = __builtin_amdgcn_mfma_f32_16x16x32_bf16(a, bfrag(Wu2, kt, nt, lane), accU[nt], 0, 0, 0);
    }
  }

#pragma unroll
  for (int nt = 0; nt < 8; ++nt) {
    int col = nt * 16 + lr;
    float b2v = bu2[col];
#pragma unroll
    for (int r = 0; r < 4; ++r) {
      int row = n0 + wave * 16 + lgp * 4 + r;
      float xv = (row < NN) ? x[(long)row * HH + col] : 0.f;
      float u = accU[nt][r] + b2v;
      float g = accG[nt][r];
      accU[nt][r] = g * u + (1.f - g) * xv;
    }
  }

#pragma unroll
  for (int r = 0; r < 4; ++r) {
    int row = n0 + wave * 16 + lgp * 4 + r;
    float s = 0.f;
#pragma unroll
    for (int nt = 0; nt < 8; ++nt) s += accU[nt][r];
    s += __shfl_xor(s, 1, 64);
    s += __shfl_xor(s, 2, 64);
    s += __shfl_xor(s, 4, 64);
    s += __shfl_xor(s, 8, 64);
    float mu = s * (1.f / 128.f);
    float qv = 0.f;
#pragma unroll
    for (int nt = 0; nt < 8; ++nt) {
      float d = accU[nt][r] - mu;
      qv += d * d;
    }
    qv += __shfl_xor(qv, 1, 64);
    qv += __shfl_xor(qv, 2, 64);
    qv += __shfl_xor(qv, 4, 64);
    qv += __shfl_xor(qv, 8, 64);
    float rs = rsqrtf(qv * (1.f / 128.f) + 1e-5f);
    if (row < NN) {
#pragma unroll
      for (int nt = 0; nt < 8; ++nt) {
        int col = nt * 16 + lr;
        out[(long)row * HH + col] = (accU[nt][r] - mu) * rs * gamma[col] + beta[col];
      }
    }
  }
}

extern "C" void kernel_launch(void* const* d_in, const int* in_sizes, int n_in,
                              void* d_out, int out_size, void* d_ws, size_t ws_size,
                              hipStream_t stream) {
  const float* x = (const float*)d_in[0];
  const int* ei_l = (const int*)d_in[1];
  const float* ea_l = (const float*)d_in[2];
  const int* ei_m = (const int*)d_in[3];
  const float* ea_m = (const float*)d_in[4];
  const int* ei_g = (const int*)d_in[5];
  const float* ea_g = (const float*)d_in[6];
  const float* Wa1 = (const float*)d_in[7];
  const float* ba1 = (const float*)d_in[8];
  const float* Wa2 = (const float*)d_in[9];
  const float* ba2 = (const float*)d_in[10];
  const float* Wb1 = (const float*)d_in[11];
  const float* bb1 = (const float*)d_in[12];
  const float* Wb2 = (const float*)d_in[13];
  const float* bb2 = (const float*)d_in[14];
  const float* Wc1 = (const float*)d_in[15];
  const float* bc1 = (const float*)d_in[16];
  const float* Wc2 = (const float*)d_in[17];
  const float* bc2 = (const float*)d_in[18];
  const float* Wg = (const float*)d_in[19];
  const float* bg = (const float*)d_in[20];
  const float* Wu1 = (const float*)d_in[21];
  const float* bu1 = (const float*)d_in[22];
  const float* Wu2 = (const float*)d_in[23];
  const float* bu2 = (const float*)d_in[24];
  const float* gamma = (const float*)d_in[25];
  const float* beta = (const float*)d_in[26];

  const int El = in_sizes[1] / 2;
  const int Em = in_sizes[3] / 2;
  const int Eg = in_sizes[5] / 2;
  const int Etot = El + Em + Eg;

  // Workspace layout
  float* hl = (float*)d_ws;                  // hagg [N][128] f32 per scale
  float* hm = hl + (size_t)NN * HH;
  float* hg = hm + (size_t)NN * HH;
  unsigned short* wp = (unsigned short*)(hg + (size_t)NN * HH);
  unsigned short* W1a_a = wp; wp += 128 * 128;
  unsigned short* W1b_a = wp; wp += 128 * 128;
  unsigned short* W2_a  = wp; wp += 128 * 128;
  unsigned short* W1a_b = wp; wp += 128 * 128;
  unsigned short* W1b_b = wp; wp += 128 * 128;
  unsigned short* W2_b  = wp; wp += 128 * 128;
  unsigned short* W1a_c = wp; wp += 128 * 128;
  unsigned short* W1b_c = wp; wp += 128 * 128;
  unsigned short* W2_c  = wp; wp += 128 * 128;
  unsigned short* Wu2_s = wp; wp += 128 * 128;
  unsigned short* Wg_s  = wp; wp += 512 * 128;
  unsigned short* Wu1_s = wp; wp += 512 * 128;
  unsigned short* xb  = wp; wp += (size_t)NN * HH;
  unsigned short* P_l = wp; wp += (size_t)NN * HH;
  unsigned short* Q_l = wp; wp += (size_t)NN * HH;
  unsigned short* P_m = wp; wp += (size_t)NN * HH;
  unsigned short* Q_m = wp; wp += (size_t)NN * HH;
  unsigned short* P_g = wp; wp += (size_t)NN * HH;
  unsigned short* Q_g = wp; wp += (size_t)NN * HH;
  // M buffers alias the P buffers (P dead after edge_kernel; stream order guarantees safety)
  unsigned short* M_l = P_l;
  unsigned short* M_m = P_m;
  unsigned short* M_g = P_g;
  int* ip = (int*)wp;
  int* cnt  = ip; ip += 3 * NN;   // histogram (kept -> degrees for msg kernel)
  int* offs = ip; ip += 3 * NN;
  int* bsum = ip; ip += 256;
  int* ssrc = ip; ip += Etot;
  int* sdst = ip; ip += Etot;
  size_t off16 = ((size_t)((char*)ip - (char*)d_ws) + 15) & ~(size_t)15;
  float4* sea = (float4*)((char*)d_ws + off16);   // Etot float4

  hipMemsetAsync(d_ws, 0, (size_t)3 * NN * HH * sizeof(float), stream);
  hipMemsetAsync(cnt, 0, 3 * NN * sizeof(int), stream);

  // Weight swizzles
  SwzJobs jobs;
  jobs.src[0] = Wa1;            jobs.dst[0] = W1a_a;
  jobs.src[1] = Wa1 + 128*128;  jobs.dst[1] = W1b_a;
  jobs.src[2] = Wa2;            jobs.dst[2] = W2_a;
  jobs.src[3] = Wb1;            jobs.dst[3] = W1a_b;
  jobs.src[4] = Wb1 + 128*128;  jobs.dst[4] = W1b_b;
  jobs.src[5] = Wb2;            jobs.dst[5] = W2_b;
  jobs.src[6] = Wc1;            jobs.dst[6] = W1a_c;
  jobs.src[7] = Wc1 + 128*128;  jobs.dst[7] = W1b_c;
  jobs.src[8] = Wc2;            jobs.dst[8] = W2_c;
  jobs.src[9] = Wu2;            jobs.dst[9] = Wu2_s;
  jobs.src[10] = Wg;            jobs.dst[10] = Wg_s;
  jobs.src[11] = Wu1;           jobs.dst[11] = Wu1_s;
  swz_all_kernel<<<640 + 512, 256, 0, stream>>>(jobs);

  // P/Q precompute (P = x@W1a; Q = x@W1b + b1) + xb write-out
  PQJobs pq;
  pq.Wswz[0] = W1a_a; pq.bias[0] = nullptr; pq.out[0] = P_l;
  pq.Wswz[1] = W1b_a; pq.bias[1] = ba1;     pq.out[1] = Q_l;
  pq.Wswz[2] = W1a_b; pq.bias[2] = nullptr; pq.out[2] = P_m;
  pq.Wswz[3] = W1b_b; pq.bias[3] = bb1;     pq.out[3] = Q_m;
  pq.Wswz[4] = W1a_c; pq.bias[4] = nullptr; pq.out[4] = P_g;
  pq.Wswz[5] = W1b_c; pq.bias[5] = bc1;     pq.out[5] = Q_g;
  pq_kernel<<<(NN + 63) / 64, 256, 0, stream>>>(x, xb, pq);

  // Counting sort by dst (materializes sorted ssrc/sdst/sea)
  hist3_kernel<<<(Etot + 255) / 256, 256, 0, stream>>>(ei_l, ei_m, ei_g, El, Em, Eg, cnt);
  const int n3 = 3 * NN;
  const int nblkA = (n3 + 1023) / 1024;
  scanA_kernel<<<nblkA, 1024, 0, stream>>>(cnt, offs, bsum, n3);
  scanB_kernel<<<1, 256, 0, stream>>>(bsum, nblkA);
  scanC_kernel<<<nblkA, 1024, 0, stream>>>(offs, bsum, n3);
  scatter3_kernel<<<(Etot + 255) / 256, 256, 0, stream>>>(
      ei_l, ei_m, ei_g, ea_l, ea_m, ea_g, El, Em, Eg, offs, ssrc, sdst, sea);

  // Edge pass: segment-summed h1 into hagg buffers (one launch, 3 scales)
  const int ntl = (El + EB - 1) / EB, ntm = (Em + EB - 1) / EB, ntg = (Eg + EB - 1) / EB;
  EParams ep;
  ep.s[0] = {ssrc,           sdst,           sea,           P_l, Q_l, Wa1 + 256 * 128, hl, El, 0};
  ep.s[1] = {ssrc + El,      sdst + El,      sea + El,      P_m, Q_m, Wb1 + 256 * 128, hm, Em, ntl};
  ep.s[2] = {ssrc + El + Em, sdst + El + Em, sea + El + Em, P_g, Q_g, Wc1 + 256 * 128, hg, Eg, ntl + ntm};
  edge_kernel<<<ntl + ntm + ntg, 256, 0, stream>>>(ep);

  // Msg pass: M_s = bf16(hagg_s @ W2_s + deg*b2_s)
  MsgParams mp;
  mp.s[0] = {hl, W2_a, ba2, cnt,          M_l};
  mp.s[1] = {hm, W2_b, bb2, cnt + NN,     M_m};
  mp.s[2] = {hg, W2_c, bc2, cnt + 2 * NN, M_g};
  const int NB = (NN + 63) / 64;
  msg_kernel<<<3 * NB, 256, 0, stream>>>(mp);

  // Node update + LayerNorm (all-bf16 A-stream)
  node_kernel<<<NB, 256, 0, stream>>>(x, xb, M_l, M_m, M_g, Wg_s, Wu1_s, Wu2_s,
                                      bg, bu1, bu2, gamma, beta, (float*)d_out);
}

// Round 9
// 384.244 us; speedup vs baseline: 1.5658x; 1.2490x over previous
//
#include <hip/hip_runtime.h>

typedef __attribute__((ext_vector_type(8))) short bf16x8;
typedef __attribute__((ext_vector_type(8))) unsigned short ushort8;
typedef __attribute__((ext_vector_type(4))) float f32x4;

#define NN 50000
#define HH 128

static __device__ __forceinline__ unsigned short f2bf(float f) {
  unsigned u = __builtin_bit_cast(unsigned, f);
  u = u + 0x7FFFu + ((u >> 16) & 1u);
  return (unsigned short)(u >> 16);
}

static __device__ __forceinline__ float bf2f(unsigned short b) {
  return __builtin_bit_cast(float, ((unsigned)b) << 16);
}

static __device__ __forceinline__ bf16x8 bfrag(const unsigned short* __restrict__ w,
                                               int kt, int nt, int lane) {
  return *reinterpret_cast<const bf16x8*>(w + (((kt * 8 + nt) * 64 + lane) << 3));
}

// Fused weight swizzle: 10 jobs with K=128 (64 blocks each), 2 jobs with K=512 (256 blocks).
struct SwzJobs {
  const float* src[12];
  unsigned short* dst[12];
};
__global__ void swz_all_kernel(SwzJobs jobs) {
  int b = blockIdx.x;
  int job, blk;
  if (b < 640) { job = b >> 6; blk = b & 63; }
  else { b -= 640; job = 10 + (b >> 8); blk = b & 255; }
  int o = blk * 256 + threadIdx.x;
  int j = o & 7, lane = (o >> 3) & 63, nt = (o >> 9) & 7, kt = o >> 12;
  int row = kt * 32 + (lane >> 4) * 8 + j;
  int col = nt * 16 + (lane & 15);
  jobs.dst[job][o] = f2bf(jobs.src[job][row * 128 + col]);
}

// P/Q precompute: 6 GEMMs out = x @ W (+bias), bf16 row-major output; also writes xb.
struct PQJobs {
  const unsigned short* Wswz[6];
  const float* bias[6];
  unsigned short* out[6];
};
__global__ __launch_bounds__(256) void pq_kernel(const float* __restrict__ x,
                                                 unsigned short* __restrict__ xb,
                                                 PQJobs jobs) {
  __shared__ unsigned short As[64][136];
  const int t = threadIdx.x;
  const int n0 = blockIdx.x * 64;
  for (int idx = t; idx < 64 * 32; idx += 256) {
    int e = idx >> 5, c4 = (idx & 31) << 2;
    int row = n0 + e;
    float4 v = make_float4(0.f, 0.f, 0.f, 0.f);
    if (row < NN) v = *reinterpret_cast<const float4*>(x + (long)row * HH + c4);
    *reinterpret_cast<ushort4*>(&As[e][c4]) =
        make_ushort4(f2bf(v.x), f2bf(v.y), f2bf(v.z), f2bf(v.w));
  }
  __syncthreads();
  for (int idx = t; idx < 64 * 32; idx += 256) {
    int e = idx >> 5, c4 = (idx & 31) << 2;
    int row = n0 + e;
    if (row < NN)
      *reinterpret_cast<ushort4*>(xb + (long)row * HH + c4) =
          *reinterpret_cast<const ushort4*>(&As[e][c4]);
  }
  const int wave = t >> 6, lane = t & 63;
  const int lr = lane & 15, lgp = lane >> 4;
  bf16x8 afr[4];
#pragma unroll
  for (int kt = 0; kt < 4; ++kt)
    afr[kt] = *reinterpret_cast<const bf16x8*>(&As[wave * 16 + lr][kt * 32 + lgp * 8]);
#pragma unroll
  for (int jb = 0; jb < 6; ++jb) {
    f32x4 acc[8];
#pragma unroll
    for (int nt = 0; nt < 8; ++nt) acc[nt] = (f32x4){0.f, 0.f, 0.f, 0.f};
#pragma unroll
    for (int kt = 0; kt < 4; ++kt)
#pragma unroll
      for (int nt = 0; nt < 8; ++nt)
        acc[nt] = __builtin_amdgcn_mfma_f32_16x16x32_bf16(
            afr[kt], bfrag(jobs.Wswz[jb], kt, nt, lane), acc[nt], 0, 0, 0);
    const float* bi = jobs.bias[jb];
    unsigned short* O = jobs.out[jb];
#pragma unroll
    for (int nt = 0; nt < 8; ++nt) {
      int col = nt * 16 + lr;
      float bv = bi ? bi[col] : 0.f;
#pragma unroll
      for (int r = 0; r < 4; ++r) {
        int row = n0 + wave * 16 + lgp * 4 + r;
        if (row < NN) O[(long)row * HH + col] = f2bf(acc[nt][r] + bv);
      }
    }
  }
}

// ---- counting-sort by destination (two-level parallel scan) ----
__global__ void hist3_kernel(const int* __restrict__ eiL, const int* __restrict__ eiM,
                             const int* __restrict__ eiG, int El, int Em, int Eg,
                             int* __restrict__ cnt) {
  int e = blockIdx.x * 256 + threadIdx.x;
  const int* ei; int E, off;
  if (e < El) { ei = eiL; E = El; off = 0; }
  else if (e < El + Em) { e -= El; ei = eiM; E = Em; off = NN; }
  else { e -= El + Em; if (e >= Eg) return; ei = eiG; E = Eg; off = 2 * NN; }
  atomicAdd(cnt + off + ei[E + e], 1);
}

__global__ void scanA_kernel(const int* __restrict__ cnt, int* __restrict__ offs,
                             int* __restrict__ bsum, int n) {
  const int t = threadIdx.x, lane = t & 63, w = t >> 6;
  const int i = blockIdx.x * 1024 + t;
  __shared__ int wsum[16], wpre[16];
  int v = (i < n) ? cnt[i] : 0;
  int inc = v;
#pragma unroll
  for (int d = 1; d < 64; d <<= 1) {
    int o = __shfl_up(inc, d, 64);
    if (lane >= d) inc += o;
  }
  if (lane == 63) wsum[w] = inc;
  __syncthreads();
  if (t == 0) {
    int run = 0;
#pragma unroll
    for (int k = 0; k < 16; ++k) { wpre[k] = run; run += wsum[k]; }
    wsum[0] = run;
  }
  __syncthreads();
  if (i < n) offs[i] = wpre[w] + inc - v;
  if (t == 0) bsum[blockIdx.x] = wsum[0];
}

__global__ void scanB_kernel(int* __restrict__ bsum, int n) {
  const int t = threadIdx.x, lane = t & 63, w = t >> 6;
  __shared__ int wsum[4];
  int v = (t < n) ? bsum[t] : 0;
  int inc = v;
#pragma unroll
  for (int d = 1; d < 64; d <<= 1) {
    int o = __shfl_up(inc, d, 64);
    if (lane >= d) inc += o;
  }
  if (lane == 63) wsum[w] = inc;
  __syncthreads();
  int wo = 0;
  for (int k = 0; k < w; ++k) wo += wsum[k];
  if (t < n) bsum[t] = wo + inc - v;
}

// adds block offsets; writes result to BOTH offs (consumed by scatter) and rowptr (kept)
__global__ void scanC_kernel(int* __restrict__ offs, int* __restrict__ rowptr,
                             const int* __restrict__ bsum, int n) {
  int i = blockIdx.x * 1024 + threadIdx.x;
  if (i < n) {
    int v = offs[i] + bsum[blockIdx.x];
    offs[i] = v;
    rowptr[i] = v;
  }
}

// Scatter into GLOBAL sorted position: materialize sorted src/edge-attr arrays.
__global__ void scatter3_kernel(const int* __restrict__ eiL, const int* __restrict__ eiM,
                                const int* __restrict__ eiG,
                                const float* __restrict__ eaL, const float* __restrict__ eaM,
                                const float* __restrict__ eaG,
                                int El, int Em, int Eg, int* __restrict__ offs,
                                int* __restrict__ ssrc, float4* __restrict__ sea) {
  int e = blockIdx.x * 256 + threadIdx.x;
  const int* ei; const float* ea; int E, off;
  if (e < El) { ei = eiL; ea = eaL; E = El; off = 0; }
  else if (e < El + Em) { e -= El; ei = eiM; ea = eaM; E = Em; off = NN; }
  else { e -= El + Em; if (e >= Eg) return; ei = eiG; ea = eaG; E = Eg; off = 2 * NN; }
  int d = ei[E + e];
  int p = atomicAdd(offs + off + d, 1);
  ssrc[p] = ei[e];
  sea[p] = make_float4(ea[(long)e * 3 + 0], ea[(long)e * 3 + 1], ea[(long)e * 3 + 2], 0.f);
}

// ---- edge kernel: one WAVE per dst (CSR run). hagg[dst] = bf16(sum relu(P[src]+Q[dst]+ea·Wc))
// Plain stores, zero atomics, no LDS, no barriers. Lane owns 2 columns.
struct EScale2 { const unsigned short *P, *Q; const float* Wc; unsigned short* hag; };
struct EParams2 {
  EScale2 s[3];
  const int* ssrc; const float4* sea;
  const int* rowptr; const int* cnt;
};
__global__ __launch_bounds__(256) void edge_kernel(EParams2 prm) {
  const int t = threadIdx.x;
  const int wave = t >> 6, lane = t & 63;
  const int gid = blockIdx.x * 4 + wave;        // [0, 3*NN)
  if (gid >= 3 * NN) return;
  const int si = gid / NN;                       // wave-uniform
  const int dst = gid - si * NN;
  const EScale2 S = prm.s[si];
  const int base = prm.rowptr[gid];
  const int len = prm.cnt[gid];
  const int c2 = lane * 2;

  const float wcA0 = S.Wc[c2],       wcB0 = S.Wc[c2 + 1];
  const float wcA1 = S.Wc[128 + c2], wcB1 = S.Wc[129 + c2];
  const float wcA2 = S.Wc[256 + c2], wcB2 = S.Wc[257 + c2];

  float aA = 0.f, aB = 0.f;
  if (len > 0) {
    ushort2 qv = *reinterpret_cast<const ushort2*>(S.Q + (long)dst * HH + c2);
    const float qA = bf2f(qv.x), qB = bf2f(qv.y);
    const int* __restrict__ sp = prm.ssrc + base;
    const float4* __restrict__ ep = prm.sea + base;
    int i = 0;
    const int n4 = len & ~3;
    for (; i < n4; i += 4) {
      int s0 = sp[i], s1 = sp[i + 1], s2 = sp[i + 2], s3 = sp[i + 3];
      float4 a0 = ep[i], a1 = ep[i + 1], a2 = ep[i + 2], a3 = ep[i + 3];
      ushort2 p0 = *reinterpret_cast<const ushort2*>(S.P + (long)s0 * HH + c2);
      ushort2 p1 = *reinterpret_cast<const ushort2*>(S.P + (long)s1 * HH + c2);
      ushort2 p2 = *reinterpret_cast<const ushort2*>(S.P + (long)s2 * HH + c2);
      ushort2 p3 = *reinterpret_cast<const ushort2*>(S.P + (long)s3 * HH + c2);
      aA += fmaxf(bf2f(p0.x) + qA + a0.x * wcA0 + a0.y * wcA1 + a0.z * wcA2, 0.f);
      aB += fmaxf(bf2f(p0.y) + qB + a0.x * wcB0 + a0.y * wcB1 + a0.z * wcB2, 0.f);
      aA += fmaxf(bf2f(p1.x) + qA + a1.x * wcA0 + a1.y * wcA1 + a1.z * wcA2, 0.f);
      aB += fmaxf(bf2f(p1.y) + qB + a1.x * wcB0 + a1.y * wcB1 + a1.z * wcB2, 0.f);
      aA += fmaxf(bf2f(p2.x) + qA + a2.x * wcA0 + a2.y * wcA1 + a2.z * wcA2, 0.f);
      aB += fmaxf(bf2f(p2.y) + qB + a2.x * wcB0 + a2.y * wcB1 + a2.z * wcB2, 0.f);
      aA += fmaxf(bf2f(p3.x) + qA + a3.x * wcA0 + a3.y * wcA1 + a3.z * wcA2, 0.f);
      aB += fmaxf(bf2f(p3.y) + qB + a3.x * wcB0 + a3.y * wcB1 + a3.z * wcB2, 0.f);
    }
    for (; i < len; ++i) {
      int s0 = sp[i];
      float4 a0 = ep[i];
      ushort2 p0 = *reinterpret_cast<const ushort2*>(S.P + (long)s0 * HH + c2);
      aA += fmaxf(bf2f(p0.x) + qA + a0.x * wcA0 + a0.y * wcA1 + a0.z * wcA2, 0.f);
      aB += fmaxf(bf2f(p0.y) + qB + a0.x * wcB0 + a0.y * wcB1 + a0.z * wcB2, 0.f);
    }
  }
  *reinterpret_cast<ushort2*>(S.hag + (long)dst * HH + c2) = make_ushort2(f2bf(aA), f2bf(aB));
}

// ---- msg kernel: M_s = bf16(hagg_s @ W2_s + deg_s*b2_s); A-frags straight from bf16 hagg ----
struct MsgScale {
  const unsigned short* H; const unsigned short* W2s; const float* b2; const int* deg;
  unsigned short* M;
};
struct MsgParams { MsgScale s[3]; };
__global__ __launch_bounds__(256) void msg_kernel(MsgParams prm) {
  const int bid = blockIdx.x;
  const int si = bid % 3;
  const int n0 = (bid / 3) * 64;
  const MsgScale S = prm.s[si];
  const int t = threadIdx.x;
  const int wave = t >> 6, lane = t & 63;
  const int lr = lane & 15, lgp = lane >> 4;
  const int arow = n0 + wave * 16 + lr;
  const bool aok = arow < NN;
  f32x4 acc[8];
#pragma unroll
  for (int nt = 0; nt < 8; ++nt) acc[nt] = (f32x4){0.f, 0.f, 0.f, 0.f};
#pragma unroll
  for (int kt = 0; kt < 4; ++kt) {
    bf16x8 a = (bf16x8){0, 0, 0, 0, 0, 0, 0, 0};
    if (aok)
      a = *reinterpret_cast<const bf16x8*>(S.H + (long)arow * HH + kt * 32 + lgp * 8);
#pragma unroll
    for (int nt = 0; nt < 8; ++nt)
      acc[nt] = __builtin_amdgcn_mfma_f32_16x16x32_bf16(
          a, bfrag(S.W2s, kt, nt, lane), acc[nt], 0, 0, 0);
  }
#pragma unroll
  for (int nt = 0; nt < 8; ++nt) {
    int col = nt * 16 + lr;
    float bv = S.b2[col];
#pragma unroll
    for (int r = 0; r < 4; ++r) {
      int row = n0 + wave * 16 + lgp * 4 + r;
      if (row < NN) {
        float dg = (float)S.deg[row];
        S.M[(long)row * HH + col] = f2bf(acc[nt][r] + dg * bv);
      }
    }
  }
}

// ---- node kernel: streaming K=512 over bf16 [xb|Ml|Mm|Mg], two GEMMs + Wu2 + LN ----
__global__ __launch_bounds__(256) void node_kernel(
    const float* __restrict__ x, const unsigned short* __restrict__ xb,
    const unsigned short* __restrict__ Ml, const unsigned short* __restrict__ Mm,
    const unsigned short* __restrict__ Mg,
    const unsigned short* __restrict__ Wg, const unsigned short* __restrict__ Wu1,
    const unsigned short* __restrict__ Wu2,
    const float* __restrict__ bg, const float* __restrict__ bu1, const float* __restrict__ bu2,
    const float* __restrict__ gamma, const float* __restrict__ beta,
    float* __restrict__ out) {
  __shared__ unsigned short Hs[64][136];
  const int t = threadIdx.x;
  const int n0 = blockIdx.x * 64;
  const int wave = t >> 6, lane = t & 63;
  const int lr = lane & 15, lgp = lane >> 4;

  f32x4 accG[8], accH[8];
#pragma unroll
  for (int nt = 0; nt < 8; ++nt) {
    accG[nt] = (f32x4){0.f, 0.f, 0.f, 0.f};
    accH[nt] = (f32x4){0.f, 0.f, 0.f, 0.f};
  }
  const int arow = n0 + wave * 16 + lr;
  const bool aok = arow < NN;

#pragma unroll
  for (int kt = 0; kt < 16; ++kt) {
    const unsigned short* S = (kt < 4) ? xb : (kt < 8) ? Ml : (kt < 12) ? Mm : Mg;
    int cb = ((kt & 3) << 5) + (lgp << 3);
    bf16x8 a = (bf16x8){0, 0, 0, 0, 0, 0, 0, 0};
    if (aok) a = *reinterpret_cast<const bf16x8*>(S + (long)arow * HH + cb);
#pragma unroll
    for (int nt = 0; nt < 8; ++nt) {
      accG[nt] = __builtin_amdgcn_mfma_f32_16x16x32_bf16(a, bfrag(Wg, kt, nt, lane), accG[nt], 0, 0, 0);
      accH[nt] = __builtin_amdgcn_mfma_f32_16x16x32_bf16(a, bfrag(Wu1, kt, nt, lane), accH[nt], 0, 0, 0);
    }
  }

#pragma unroll
  for (int nt = 0; nt < 8; ++nt) {
    int col = nt * 16 + lr;
    float bgv = bg[col], bhv = bu1[col];
#pragma unroll
    for (int r = 0; r < 4; ++r) {
      float g = 1.f / (1.f + __expf(-(accG[nt][r] + bgv)));
      accG[nt][r] = g;
      float h = fmaxf(accH[nt][r] + bhv, 0.f);
      Hs[wave * 16 + lgp * 4 + r][col] = f2bf(h);
    }
  }

  f32x4 accU[8];
#pragma unroll
  for (int nt = 0; nt < 8; ++nt) accU[nt] = (f32x4){0.f, 0.f, 0.f, 0.f};
#pragma unroll
  for (int kt = 0; kt < 4; ++kt) {
    bf16x8 a = *reinterpret_cast<const bf16x8*>(&Hs[wave * 16 + lr][kt * 32 + lgp * 8]);
#pragma unroll
    for (int nt = 0; nt < 8; ++nt) {
      accU[nt] = __builtin_amdgcn_mfma_f32_16x16x32_bf16(a, bfrag(Wu2, kt, nt, lane), accU[nt], 0, 0, 0);
    }
  }

#pragma unroll
  for (int nt = 0; nt < 8; ++nt) {
    int col = nt * 16 + lr;
    float b2v = bu2[col];
#pragma unroll
    for (int r = 0; r < 4; ++r) {
      int row = n0 + wave * 16 + lgp * 4 + r;
      float xv = (row < NN) ? x[(long)row * HH + col] : 0.f;
      float u = accU[nt][r] + b2v;
      float g = accG[nt][r];
      accU[nt][r] = g * u + (1.f - g) * xv;
    }
  }

#pragma unroll
  for (int r = 0; r < 4; ++r) {
    int row = n0 + wave * 16 + lgp * 4 + r;
    float s = 0.f;
#pragma unroll
    for (int nt = 0; nt < 8; ++nt) s += accU[nt][r];
    s += __shfl_xor(s, 1, 64);
    s += __shfl_xor(s, 2, 64);
    s += __shfl_xor(s, 4, 64);
    s += __shfl_xor(s, 8, 64);
    float mu = s * (1.f / 128.f);
    float qv = 0.f;
#pragma unroll
    for (int nt = 0; nt < 8; ++nt) {
      float d = accU[nt][r] - mu;
      qv += d * d;
    }
    qv += __shfl_xor(qv, 1, 64);
    qv += __shfl_xor(qv, 2, 64);
    qv += __shfl_xor(qv, 4, 64);
    qv += __shfl_xor(qv, 8, 64);
    float rs = rsqrtf(qv * (1.f / 128.f) + 1e-5f);
    if (row < NN) {
#pragma unroll
      for (int nt = 0; nt < 8; ++nt) {
        int col = nt * 16 + lr;
        out[(long)row * HH + col] = (accU[nt][r] - mu) * rs * gamma[col] + beta[col];
      }
    }
  }
}

extern "C" void kernel_launch(void* const* d_in, const int* in_sizes, int n_in,
                              void* d_out, int out_size, void* d_ws, size_t ws_size,
                              hipStream_t stream) {
  const float* x = (const float*)d_in[0];
  const int* ei_l = (const int*)d_in[1];
  const float* ea_l = (const float*)d_in[2];
  const int* ei_m = (const int*)d_in[3];
  const float* ea_m = (const float*)d_in[4];
  const int* ei_g = (const int*)d_in[5];
  const float* ea_g = (const float*)d_in[6];
  const float* Wa1 = (const float*)d_in[7];
  const float* ba1 = (const float*)d_in[8];
  const float* Wa2 = (const float*)d_in[9];
  const float* ba2 = (const float*)d_in[10];
  const float* Wb1 = (const float*)d_in[11];
  const float* bb1 = (const float*)d_in[12];
  const float* Wb2 = (const float*)d_in[13];
  const float* bb2 = (const float*)d_in[14];
  const float* Wc1 = (const float*)d_in[15];
  const float* bc1 = (const float*)d_in[16];
  const float* Wc2 = (const float*)d_in[17];
  const float* bc2 = (const float*)d_in[18];
  const float* Wg = (const float*)d_in[19];
  const float* bg = (const float*)d_in[20];
  const float* Wu1 = (const float*)d_in[21];
  const float* bu1 = (const float*)d_in[22];
  const float* Wu2 = (const float*)d_in[23];
  const float* bu2 = (const float*)d_in[24];
  const float* gamma = (const float*)d_in[25];
  const float* beta = (const float*)d_in[26];

  const int El = in_sizes[1] / 2;
  const int Em = in_sizes[3] / 2;
  const int Eg = in_sizes[5] / 2;
  const int Etot = El + Em + Eg;

  // Workspace layout (hagg now bf16)
  unsigned short* wp = (unsigned short*)d_ws;
  unsigned short* hl = wp; wp += (size_t)NN * HH;
  unsigned short* hm = wp; wp += (size_t)NN * HH;
  unsigned short* hg = wp; wp += (size_t)NN * HH;
  unsigned short* W1a_a = wp; wp += 128 * 128;
  unsigned short* W1b_a = wp; wp += 128 * 128;
  unsigned short* W2_a  = wp; wp += 128 * 128;
  unsigned short* W1a_b = wp; wp += 128 * 128;
  unsigned short* W1b_b = wp; wp += 128 * 128;
  unsigned short* W2_b  = wp; wp += 128 * 128;
  unsigned short* W1a_c = wp; wp += 128 * 128;
  unsigned short* W1b_c = wp; wp += 128 * 128;
  unsigned short* W2_c  = wp; wp += 128 * 128;
  unsigned short* Wu2_s = wp; wp += 128 * 128;
  unsigned short* Wg_s  = wp; wp += 512 * 128;
  unsigned short* Wu1_s = wp; wp += 512 * 128;
  unsigned short* xb  = wp; wp += (size_t)NN * HH;
  unsigned short* P_l = wp; wp += (size_t)NN * HH;
  unsigned short* Q_l = wp; wp += (size_t)NN * HH;
  unsigned short* P_m = wp; wp += (size_t)NN * HH;
  unsigned short* Q_m = wp; wp += (size_t)NN * HH;
  unsigned short* P_g = wp; wp += (size_t)NN * HH;
  unsigned short* Q_g = wp; wp += (size_t)NN * HH;
  unsigned short* M_l = P_l;   // alias (P dead after edge_kernel)
  unsigned short* M_m = P_m;
  unsigned short* M_g = P_g;
  int* ip = (int*)wp;
  int* cnt    = ip; ip += 3 * NN;   // degrees (kept)
  int* offs   = ip; ip += 3 * NN;   // consumed by scatter
  int* rowptr = ip; ip += 3 * NN;   // kept for edge kernel
  int* bsum   = ip; ip += 256;
  int* ssrc   = ip; ip += Etot;
  size_t off16 = ((size_t)((char*)ip - (char*)d_ws) + 15) & ~(size_t)15;
  float4* sea = (float4*)((char*)d_ws + off16);   // Etot float4

  hipMemsetAsync(cnt, 0, 3 * NN * sizeof(int), stream);

  // Weight swizzles
  SwzJobs jobs;
  jobs.src[0] = Wa1;            jobs.dst[0] = W1a_a;
  jobs.src[1] = Wa1 + 128*128;  jobs.dst[1] = W1b_a;
  jobs.src[2] = Wa2;            jobs.dst[2] = W2_a;
  jobs.src[3] = Wb1;            jobs.dst[3] = W1a_b;
  jobs.src[4] = Wb1 + 128*128;  jobs.dst[4] = W1b_b;
  jobs.src[5] = Wb2;            jobs.dst[5] = W2_b;
  jobs.src[6] = Wc1;            jobs.dst[6] = W1a_c;
  jobs.src[7] = Wc1 + 128*128;  jobs.dst[7] = W1b_c;
  jobs.src[8] = Wc2;            jobs.dst[8] = W2_c;
  jobs.src[9] = Wu2;            jobs.dst[9] = Wu2_s;
  jobs.src[10] = Wg;            jobs.dst[10] = Wg_s;
  jobs.src[11] = Wu1;           jobs.dst[11] = Wu1_s;
  swz_all_kernel<<<640 + 512, 256, 0, stream>>>(jobs);

  // P/Q precompute (P = x@W1a; Q = x@W1b + b1) + xb write-out
  PQJobs pq;
  pq.Wswz[0] = W1a_a; pq.bias[0] = nullptr; pq.out[0] = P_l;
  pq.Wswz[1] = W1b_a; pq.bias[1] = ba1;     pq.out[1] = Q_l;
  pq.Wswz[2] = W1a_b; pq.bias[2] = nullptr; pq.out[2] = P_m;
  pq.Wswz[3] = W1b_b; pq.bias[3] = bb1;     pq.out[3] = Q_m;
  pq.Wswz[4] = W1a_c; pq.bias[4] = nullptr; pq.out[4] = P_g;
  pq.Wswz[5] = W1b_c; pq.bias[5] = bc1;     pq.out[5] = Q_g;
  pq_kernel<<<(NN + 63) / 64, 256, 0, stream>>>(x, xb, pq);

  // Counting sort by dst (materializes sorted ssrc/sea + rowptr)
  hist3_kernel<<<(Etot + 255) / 256, 256, 0, stream>>>(ei_l, ei_m, ei_g, El, Em, Eg, cnt);
  const int n3 = 3 * NN;
  const int nblkA = (n3 + 1023) / 1024;
  scanA_kernel<<<nblkA, 1024, 0, stream>>>(cnt, offs, bsum, n3);
  scanB_kernel<<<1, 256, 0, stream>>>(bsum, nblkA);
  scanC_kernel<<<nblkA, 1024, 0, stream>>>(offs, rowptr, bsum, n3);
  scatter3_kernel<<<(Etot + 255) / 256, 256, 0, stream>>>(
      ei_l, ei_m, ei_g, ea_l, ea_m, ea_g, El, Em, Eg, offs, ssrc, sea);

  // Edge pass: one wave per dst, plain bf16 stores (no atomics, no memset)
  EParams2 ep;
  ep.s[0] = {P_l, Q_l, Wa1 + 256 * 128, hl};
  ep.s[1] = {P_m, Q_m, Wb1 + 256 * 128, hm};
  ep.s[2] = {P_g, Q_g, Wc1 + 256 * 128, hg};
  ep.ssrc = ssrc; ep.sea = sea; ep.rowptr = rowptr; ep.cnt = cnt;
  edge_kernel<<<(3 * NN + 3) / 4, 256, 0, stream>>>(ep);

  // Msg pass: M_s = bf16(hagg_s @ W2_s + deg*b2_s)
  MsgParams mp;
  mp.s[0] = {hl, W2_a, ba2, cnt,          M_l};
  mp.s[1] = {hm, W2_b, bb2, cnt + NN,     M_m};
  mp.s[2] = {hg, W2_c, bc2, cnt + 2 * NN, M_g};
  const int NB = (NN + 63) / 64;
  msg_kernel<<<3 * NB, 256, 0, stream>>>(mp);

  // Node update + LayerNorm (all-bf16 A-stream)
  node_kernel<<<NB, 256, 0, stream>>>(x, xb, M_l, M_m, M_g, Wg_s, Wu1_s, Wu2_s,
                                      bg, bu1, bu2, gamma, beta, (float*)d_out);
}